// Round 2
// baseline (30411.810 us; speedup 1.0000x reference)
//
#include <hip/hip_runtime.h>
#include <stdint.h>

#define Bsz   4096
#define Tn    128
#define STEPS 127
#define NTH   512

typedef float f4v __attribute__((ext_vector_type(4)));

__device__ __forceinline__ float rcp_f(float x) { return __builtin_amdgcn_rcpf(x); }
__device__ __forceinline__ float tanh_f(float x) {
    float p = __expf(2.0f * x);
    return 1.0f - 2.0f * rcp_f(p + 1.0f);
}
__device__ __forceinline__ float sig_f(float x) {
    return rcp_f(1.0f + __expf(-x));
}
__device__ __forceinline__ uint32_t pack_bf2(float a, float b) {
    union { float f; uint32_t u; } ua, ub;
    ua.f = a; ub.f = b;
    uint32_t x = ua.u + (0x7fffu + ((ua.u >> 16) & 1u));
    uint32_t y = ub.u + (0x7fffu + ((ub.u >> 16) & 1u));
    return (x >> 16) | (y & 0xffff0000u);
}
__device__ __forceinline__ float bf_lo(uint32_t p) {
    union { uint32_t u; float f; } v; v.u = p << 16; return v.f;
}
__device__ __forceinline__ float bf_hi(uint32_t p) {
    union { uint32_t u; float f; } v; v.u = p & 0xffff0000u; return v.f;
}

__global__ __launch_bounds__(NTH, 4)
void dec_kernel(const float* __restrict__ X,    // (B,128,128)
                const float* __restrict__ yh,   // (B,127,1)
                const float* __restrict__ W1,   // (128,384): [:,:128]=W1h [:,128:256]=W1c [:,256:]=W1e
                const float* __restrict__ b1,   // (128)
                const float* __restrict__ W2,   // (1,128)
                const float* __restrict__ b2u,  // (1)  (softmax-invariant, unused)
                const float* __restrict__ Wih,  // (512,1)
                const float* __restrict__ Whh,  // (512,128)
                const float* __restrict__ bih,  // (512)
                const float* __restrict__ bhh,  // (512)
                const float* __restrict__ fcW,  // (1,129)
                const float* __restrict__ fcb,  // (1)
                const float* __restrict__ Wff,  // (1,256)
                const float* __restrict__ bff,  // (1)
                float* __restrict__ out)        // (B,1)
{
    const int tid  = threadIdx.x;
    const int lane = tid & 63;

    // EP rows: stride 132 floats (528B, 16B aligned); b128 reads at per-lane tB
    // distribute 4 words/bank (balanced).
    __shared__ __align__(16) float EP[Tn][132];
    // upool: setup = Xtile[16][4*36]; loop = e_part[4][128] (0..511) + hc[128] (512..639)
    __shared__ __align__(16) float upool[16 * 144];
    // h/c: chunk-padded [4 chunks][36] so the 4 qA read windows hit 16 distinct banks
    __shared__ __align__(16) float h_pad[2][144];
    __shared__ __align__(16) float c_pad[2][144];
    __shared__ __align__(16) float y_s[STEPS + 1];
    __shared__ __align__(16) float XF[Tn];
    __shared__ __align__(16) float XG[Tn];
    __shared__ __align__(16) float w2_lds[128];

    const float* Xb = X + (size_t)blockIdx.x * (Tn * 128);

    // ---------- init ----------
    if (tid < 144) { h_pad[0][tid] = 0.f; c_pad[0][tid] = 0.f; }
    if (tid < STEPS) y_s[tid] = yh[(size_t)blockIdx.x * STEPS + tid];
    if (tid < 128)   w2_lds[tid] = W2[tid];

    const int jA = tid >> 2;   // 0..127
    const int qA = tid & 3;    // chunk 0..3
    const int tB = tid & 127;  // phase-B t index
    const int qB = tid >> 7;   // phase-B h-chunk

    // ---------- XF[t] = X[t]·fcW[0:128], XG[t] = X[t]·Wff[128:256] ----------
    {
        float aF = 0.f, aG = 0.f;
        #pragma unroll
        for (int u = 0; u < 8; ++u) {
            f4v xv = *(const f4v*)(Xb + jA * 128 + qA * 32 + 4 * u);
            f4v fv = *(const f4v*)(fcW + qA * 32 + 4 * u);
            f4v gv = *(const f4v*)(Wff + 128 + qA * 32 + 4 * u);
            aF += xv[0]*fv[0] + xv[1]*fv[1] + xv[2]*fv[2] + xv[3]*fv[3];
            aG += xv[0]*gv[0] + xv[1]*gv[1] + xv[2]*gv[2] + xv[3]*gv[3];
        }
        aF += __shfl_xor(aF, 1); aF += __shfl_xor(aF, 2);
        aG += __shfl_xor(aG, 1); aG += __shfl_xor(aG, 2);
        if (qA == 0) { XF[jA] = aF; XG[jA] = aG; }
    }

    // ---------- enc_proj (one-time, fp32): EP[t][j] = X[t]·W1e[j] ----------
    {
        float w1e[32];
        #pragma unroll
        for (int u = 0; u < 8; ++u) {
            f4v w = *(const f4v*)(W1 + jA * 384 + 256 + qA * 32 + 4 * u);
            w1e[4*u] = w[0]; w1e[4*u+1] = w[1]; w1e[4*u+2] = w[2]; w1e[4*u+3] = w[3];
        }
        for (int tile = 0; tile < 8; ++tile) {
            __syncthreads();
            {   // stage 16 rows into chunk-padded Xtile (one f4 per thread)
                int t = tid >> 5, c4 = tid & 31;
                f4v v = *(const f4v*)(Xb + (tile * 16 + t) * 128 + c4 * 4);
                *(f4v*)&upool[t * 144 + (c4 >> 3) * 36 + (c4 & 7) * 4] = v;
            }
            __syncthreads();
            for (int tl = 0; tl < 16; ++tl) {
                float acc = 0.f;
                #pragma unroll
                for (int u = 0; u < 8; ++u) {
                    f4v xv = *(const f4v*)&upool[tl * 144 + qA * 36 + 4 * u];
                    acc += xv[0]*w1e[4*u] + xv[1]*w1e[4*u+1]
                         + xv[2]*w1e[4*u+2] + xv[3]*w1e[4*u+3];
                }
                acc += __shfl_xor(acc, 1);
                acc += __shfl_xor(acc, 2);
                if (qA == 0) EP[tile * 16 + tl][jA] = acc;
            }
        }
    }

    // ---------- persistent register weights (bf16-packed) ----------
    uint32_t w1h_pk[16], w1c_pk[16];
    #pragma unroll
    for (int u = 0; u < 8; ++u) {
        f4v a = *(const f4v*)(W1 + jA * 384 + qA * 32 + 4 * u);
        f4v c = *(const f4v*)(W1 + jA * 384 + 128 + qA * 32 + 4 * u);
        w1h_pk[2*u]   = pack_bf2(a[0], a[1]);  w1h_pk[2*u+1] = pack_bf2(a[2], a[3]);
        w1c_pk[2*u]   = pack_bf2(c[0], c[1]);  w1c_pk[2*u+1] = pack_bf2(c[2], c[3]);
    }
    // gate-row remap: quad lane q owns gate q of cell j=tid>>2
    const int r = (tid & 3) * 128 + (tid >> 2);
    uint32_t whh[64];  // Whh row r, in h_pad chunk order
    #pragma unroll
    for (int m = 0; m < 32; ++m) {
        int ge = (m >> 3) * 32 + (m & 7) * 4;
        f4v w = *(const f4v*)(Whh + (size_t)r * 128 + ge);
        whh[2*m]   = pack_bf2(w[0], w[1]);
        whh[2*m+1] = pack_bf2(w[2], w[3]);
    }
    const float wihv = Wih[r];
    const float bgv  = bih[r] + bhh[r];
    const float b1j  = b1[jA];
    const float fcwy = fcW[128];
    const float fcbv = fcb[0];
    const float bffv = bff[0];
    const float wh0  = Wff[lane];
    const float wh1  = Wff[lane + 64];
    float ytg_last = 0.f;
    __syncthreads();

    // ================= scan: 127 steps, 3 barriers each =================
    for (int s = 0; s < STEPS; ++s) {
        const int cur = s & 1;

        // -- A: hc[j] = b1[j] + h·W1h[j] + c·W1c[j]  (4 thr/j, quad butterfly)
        {
            float acc = 0.f;
            #pragma unroll
            for (int u = 0; u < 8; ++u) {
                f4v hv = *(const f4v*)&h_pad[cur][qA * 36 + 4 * u];
                f4v cv = *(const f4v*)&c_pad[cur][qA * 36 + 4 * u];
                uint32_t a0 = w1h_pk[2*u], a1 = w1h_pk[2*u+1];
                uint32_t c0 = w1c_pk[2*u], c1 = w1c_pk[2*u+1];
                acc += hv[0]*bf_lo(a0) + hv[1]*bf_hi(a0) + hv[2]*bf_lo(a1) + hv[3]*bf_hi(a1);
                acc += cv[0]*bf_lo(c0) + cv[1]*bf_hi(c0) + cv[2]*bf_lo(c1) + cv[3]*bf_hi(c1);
            }
            acc += __shfl_xor(acc, 1);
            acc += __shfl_xor(acc, 2);
            if (qA == 0) upool[512 + jA] = acc + b1j;   // hc
        }
        __syncthreads();

        // -- B: e_part[qB][tB] = Σ_{h in chunk} w2[h]·tanh(EP[tB][h] + hc[h])
        {
            float acc = 0.f;
            #pragma unroll
            for (int u = 0; u < 8; ++u) {
                f4v ep  = *(const f4v*)&EP[tB][qB * 32 + 4 * u];
                f4v hcv = *(const f4v*)&upool[512 + qB * 32 + 4 * u];
                f4v w2v = *(const f4v*)&w2_lds[qB * 32 + 4 * u];
                #pragma unroll
                for (int k = 0; k < 4; ++k)
                    acc += w2v[k] * tanh_f(ep[k] + hcv[k]);
            }
            upool[qB * 128 + tB] = acc;                 // e_part
        }
        __syncthreads();

        // -- S: per-wave redundant softmax + fused β·XF, β·XG (no barrier after)
        float ytc, ytg;
        {
            float v0 = upool[lane]       + upool[128 + lane]
                     + upool[256 + lane] + upool[384 + lane];
            float v1 = upool[lane + 64]  + upool[192 + lane]
                     + upool[320 + lane] + upool[448 + lane];
            float m = fmaxf(v0, v1);
            #pragma unroll
            for (int d = 1; d < 64; d <<= 1) m = fmaxf(m, __shfl_xor(m, d));
            float p0 = __expf(v0 - m), p1 = __expf(v1 - m);
            float sp = p0 + p1;
            float sf = p0 * XF[lane] + p1 * XF[lane + 64];
            float sg = p0 * XG[lane] + p1 * XG[lane + 64];
            #pragma unroll
            for (int d = 1; d < 64; d <<= 1) {
                sp += __shfl_xor(sp, d);
                sf += __shfl_xor(sf, d);
                sg += __shfl_xor(sg, d);
            }
            float inv = rcp_f(sp);
            ytc = sf * inv;
            ytg = sg * inv;
            ytg_last = ytg;
        }

        // -- D: gate pre-activation for row r; E' fused via quad shuffles
        {
            float ytilde = ytc + fcwy * y_s[s] + fcbv;
            float g = bgv + wihv * ytilde;
            #pragma unroll
            for (int m = 0; m < 32; ++m) {
                f4v hv = *(const f4v*)&h_pad[cur][(m >> 3) * 36 + (m & 7) * 4];
                uint32_t p0 = whh[2*m], p1 = whh[2*m+1];
                g += hv[0]*bf_lo(p0) + hv[1]*bf_hi(p0) + hv[2]*bf_lo(p1) + hv[3]*bf_hi(p1);
            }
            float gb = __shfl_xor(g, 1);   // quad transpose: lane q=0 gets
            float gc = __shfl_xor(g, 2);   // i=g, f=gb, g=gc, o=gd
            float gd = __shfl_xor(gb, 2);
            if ((tid & 3) == 0) {
                int j  = tid >> 2;
                int ji = (j >> 5) * 36 + (j & 31);
                float co = c_pad[cur][ji];
                float cn = sig_f(gb) * co + sig_f(g) * tanh_f(gc);
                float hn = sig_f(gd) * tanh_f(cn);
                c_pad[cur ^ 1][ji] = cn;
                h_pad[cur ^ 1][ji] = hn;
            }
        }
        __syncthreads();
    }

    // ---------- out[b] = h·Wff[0:128] + β_last·XG + bff ----------
    if (tid < 64) {
        int l0 = (lane >> 5) * 36 + (lane & 31);
        int l1 = (2 + (lane >> 5)) * 36 + (lane & 31);
        float v = h_pad[1][l0] * wh0 + h_pad[1][l1] * wh1;
        #pragma unroll
        for (int d = 1; d < 64; d <<= 1) v += __shfl_xor(v, d);
        if (lane == 0) out[blockIdx.x] = v + ytg_last + bffv;
    }
}

extern "C" void kernel_launch(void* const* d_in, const int* in_sizes, int n_in,
                              void* d_out, int out_size, void* d_ws, size_t ws_size,
                              hipStream_t stream) {
    dec_kernel<<<Bsz, NTH, 0, stream>>>(
        (const float*)d_in[0],  (const float*)d_in[1],  (const float*)d_in[2],
        (const float*)d_in[3],  (const float*)d_in[4],  (const float*)d_in[5],
        (const float*)d_in[6],  (const float*)d_in[7],  (const float*)d_in[8],
        (const float*)d_in[9],  (const float*)d_in[10], (const float*)d_in[11],
        (const float*)d_in[12], (const float*)d_in[13], (float*)d_out);
}

// Round 3
// 13294.943 us; speedup vs baseline: 2.2875x; 2.2875x over previous
//
#include <hip/hip_runtime.h>
#include <stdint.h>

#define Bsz   4096
#define STEPS 127
#define NTH   1024

typedef float f4v __attribute__((ext_vector_type(4)));

__device__ __forceinline__ float rcp_f(float x) { return __builtin_amdgcn_rcpf(x); }
__device__ __forceinline__ float tanh_f(float x) {
    float p = __expf(2.0f * x);
    return 1.0f - 2.0f * rcp_f(p + 1.0f);
}
__device__ __forceinline__ float sig_f(float x) {
    return rcp_f(1.0f + __expf(-x));
}
__device__ __forceinline__ uint32_t pack_bf2(float a, float b) {
    union { float f; uint32_t u; } ua, ub;
    ua.f = a; ub.f = b;
    uint32_t x = ua.u + (0x7fffu + ((ua.u >> 16) & 1u));
    uint32_t y = ub.u + (0x7fffu + ((ub.u >> 16) & 1u));
    return (x >> 16) | (y & 0xffff0000u);
}
__device__ __forceinline__ float bf_lo(uint32_t p) {
    union { uint32_t u; float f; } v; v.u = p << 16; return v.f;
}
__device__ __forceinline__ float bf_hi(uint32_t p) {
    union { uint32_t u; float f; } v; v.u = p & 0xffff0000u; return v.f;
}

// 1024 threads, 1 block/CU (LDS ~93KB). HW enforces <=128 VGPR for 4 waves/SIMD;
// per-thread persistent weights ~58 regs -> no spill (R2's 67GB scratch bug).
__global__ __launch_bounds__(NTH, 1)
void dec_kernel(const float* __restrict__ X,    // (B,128,128)
                const float* __restrict__ yh,   // (B,127,1)
                const float* __restrict__ W1,   // (128,384): [:,:128]=W1h [:,128:256]=W1c [:,256:]=W1e
                const float* __restrict__ b1,   // (128)
                const float* __restrict__ W2,   // (1,128)
                const float* __restrict__ b2u,  // (1) softmax-invariant, unused
                const float* __restrict__ Wih,  // (512,1)
                const float* __restrict__ Whh,  // (512,128)
                const float* __restrict__ bih,  // (512)
                const float* __restrict__ bhh,  // (512)
                const float* __restrict__ fcW,  // (1,129)
                const float* __restrict__ fcb,  // (1)
                const float* __restrict__ Wff,  // (1,256)
                const float* __restrict__ bff,  // (1)
                float* __restrict__ out)        // (B,1)
{
    const int tid  = threadIdx.x;
    const int lane = tid & 63;

    __shared__ __align__(16) float EP[128][132];     // enc_proj fp32, row 528B (16B-aligned)
    __shared__ __align__(16) float Xt[32][132];      // setup staging (transposed-swizzled f4 slots)
    __shared__ __align__(16) float state[2][288];    // concat(h,c), chunk-padded [8][36]
    __shared__ __align__(16) float e_part[8 * 128];
    __shared__ __align__(16) float hc_lds[128];
    __shared__ __align__(16) float y_s[STEPS + 1];
    __shared__ __align__(16) float XF[128];
    __shared__ __align__(16) float XG[128];
    __shared__ __align__(16) float w2_lds[128];

    const float* Xb = X + (size_t)blockIdx.x * (128 * 128);
    float* st = (float*)state;

    if (tid < 2 * 288) st[tid] = 0.f;
    if (tid < STEPS)   y_s[tid] = yh[(size_t)blockIdx.x * STEPS + tid];
    if (tid < 128)     w2_lds[tid] = W2[tid];

    const int jA = tid >> 3;   // 0..127
    const int qA = tid & 7;    // 8 threads per j

    // ---- XF[t]=X[t]·fcW[0:128], XG[t]=X[t]·Wff[128:256] (ctx eliminated algebraically) ----
    {
        float aF = 0.f, aG = 0.f;
        #pragma unroll
        for (int u = 0; u < 4; ++u) {
            f4v xv = *(const f4v*)(Xb + jA * 128 + qA * 16 + 4 * u);
            f4v fv = *(const f4v*)(fcW + qA * 16 + 4 * u);
            f4v gv = *(const f4v*)(Wff + 128 + qA * 16 + 4 * u);
            aF += xv[0]*fv[0] + xv[1]*fv[1] + xv[2]*fv[2] + xv[3]*fv[3];
            aG += xv[0]*gv[0] + xv[1]*gv[1] + xv[2]*gv[2] + xv[3]*gv[3];
        }
        aF += __shfl_xor(aF, 1); aF += __shfl_xor(aF, 2); aF += __shfl_xor(aF, 4);
        aG += __shfl_xor(aG, 1); aG += __shfl_xor(aG, 2); aG += __shfl_xor(aG, 4);
        if (qA == 0) { XF[jA] = aF; XG[jA] = aG; }
    }

    // ---- enc_proj (one-time, fp32): EP[t][j] = X[t]·W1e[j] ----
    {
        f4v w1e[4];
        #pragma unroll
        for (int u = 0; u < 4; ++u)
            w1e[u] = *(const f4v*)(W1 + jA * 384 + 256 + qA * 16 + 4 * u);
        for (int tile = 0; tile < 4; ++tile) {
            __syncthreads();
            {   // stage 32 rows; store f4 slot c4 at 8*(c4&3)+(c4>>2) so reads broadcast
                int row = tid >> 5, c4 = tid & 31;
                int c4s = 8 * (c4 & 3) + (c4 >> 2);
                *(f4v*)&Xt[row][c4s * 4] = *(const f4v*)(Xb + (tile * 32 + row) * 128 + c4 * 4);
            }
            __syncthreads();
            for (int tl = 0; tl < 32; ++tl) {
                float acc = 0.f;
                #pragma unroll
                for (int u = 0; u < 4; ++u) {
                    f4v xv = *(const f4v*)&Xt[tl][(8 * u + qA) * 4];
                    acc += xv[0]*w1e[u][0] + xv[1]*w1e[u][1]
                         + xv[2]*w1e[u][2] + xv[3]*w1e[u][3];
                }
                acc += __shfl_xor(acc, 1); acc += __shfl_xor(acc, 2); acc += __shfl_xor(acc, 4);
                if (qA == 0) EP[tile * 32 + tl][jA] = acc;
            }
        }
    }

    // ---- persistent weights (bf16-packed): 16 + 32 u32 per thread ----
    uint32_t w1pk[16];   // concat(W1h,W1c)[jA], chunk qA*32..+32
    #pragma unroll
    for (int u = 0; u < 8; ++u) {
        f4v a = *(const f4v*)(W1 + jA * 384 + qA * 32 + 4 * u);
        w1pk[2*u]   = pack_bf2(a[0], a[1]);
        w1pk[2*u+1] = pack_bf2(a[2], a[3]);
    }
    const int gate  = tid & 3;         // gate row group (i,f,g,o)
    const int halfD = (tid >> 2) & 1;  // k-half of the 128-dot
    const int jD    = tid >> 3;        // cell 0..127
    const int r     = gate * 128 + jD;
    uint32_t whh[32];                  // Whh[r][halfD*64 .. +64]
    #pragma unroll
    for (int m = 0; m < 16; ++m) {
        f4v w = *(const f4v*)(Whh + (size_t)r * 128 + halfD * 64 + (m >> 3) * 32 + (m & 7) * 4);
        whh[2*m]   = pack_bf2(w[0], w[1]);
        whh[2*m+1] = pack_bf2(w[2], w[3]);
    }
    const float wihv = halfD ? 0.f : Wih[r];
    const float bgv  = halfD ? 0.f : (bih[r] + bhh[r]);
    const float b1j  = b1[jA];
    const float fcwy = fcW[128];
    const float fcbv = fcb[0];
    const float bffv = bff[0];
    const float wh0  = Wff[lane];
    const float wh1  = Wff[lane + 64];
    float ytg_last = 0.f;
    __syncthreads();

    // ================= scan: 127 steps, 3 barriers each =================
    for (int s = 0; s < STEPS; ++s) {
        const int cur = s & 1;

        // -- A: hc[j] = b1[j] + concat(h,c)·concat(W1h,W1c)[j]  (8 thr/j)
        {
            float acc = 0.f;
            const float* sb = st + cur * 288 + (qA & 3) * 36 + (qA >> 2) * 144;
            #pragma unroll
            for (int u = 0; u < 8; ++u) {
                f4v sv = *(const f4v*)(sb + 4 * u);
                uint32_t p0 = w1pk[2*u], p1 = w1pk[2*u+1];
                acc += sv[0]*bf_lo(p0) + sv[1]*bf_hi(p0) + sv[2]*bf_lo(p1) + sv[3]*bf_hi(p1);
            }
            acc += __shfl_xor(acc, 1); acc += __shfl_xor(acc, 2); acc += __shfl_xor(acc, 4);
            if (qA == 0) hc_lds[jA] = acc + b1j;
        }
        __syncthreads();

        // -- B: e_part[qB][tB] = Σ_{h in 16-chunk} w2[h]·tanh(EP[tB][h]+hc[h])
        {
            const int tB = tid & 127, qB = tid >> 7;
            float acc = 0.f;
            #pragma unroll
            for (int u = 0; u < 4; ++u) {
                f4v ep  = *(const f4v*)&EP[tB][qB * 16 + 4 * u];
                f4v hcv = *(const f4v*)&hc_lds[qB * 16 + 4 * u];
                f4v w2v = *(const f4v*)&w2_lds[qB * 16 + 4 * u];
                #pragma unroll
                for (int k = 0; k < 4; ++k)
                    acc += w2v[k] * tanh_f(ep[k] + hcv[k]);
            }
            e_part[qB * 128 + tB] = acc;
        }
        __syncthreads();

        // -- S: redundant per-wave softmax, fused β·XF / β·XG (no barrier after)
        float ytc;
        {
            float v0 = 0.f, v1 = 0.f;
            #pragma unroll
            for (int q = 0; q < 8; ++q) {
                v0 += e_part[q * 128 + lane];
                v1 += e_part[q * 128 + 64 + lane];
            }
            float m = fmaxf(v0, v1);
            #pragma unroll
            for (int d = 1; d < 64; d <<= 1) m = fmaxf(m, __shfl_xor(m, d));
            float p0 = __expf(v0 - m), p1 = __expf(v1 - m);
            float sp = p0 + p1;
            float sf = p0 * XF[lane] + p1 * XF[lane + 64];
            float sg = p0 * XG[lane] + p1 * XG[lane + 64];
            #pragma unroll
            for (int d = 1; d < 64; d <<= 1) {
                sp += __shfl_xor(sp, d);
                sf += __shfl_xor(sf, d);
                sg += __shfl_xor(sg, d);
            }
            float inv = rcp_f(sp);
            ytc = sf * inv;
            ytg_last = sg * inv;
        }

        // -- D: half-row gate dot (2 thr/row), octet shuffles fuse LSTM update
        {
            float ytilde = ytc + fcwy * y_s[s] + fcbv;
            float g = bgv + wihv * ytilde;
            const float* hb = st + cur * 288 + halfD * 72;
            #pragma unroll
            for (int m = 0; m < 16; ++m) {
                f4v hv = *(const f4v*)(hb + (m >> 3) * 36 + (m & 7) * 4);
                uint32_t p0 = whh[2*m], p1 = whh[2*m+1];
                g += hv[0]*bf_lo(p0) + hv[1]*bf_hi(p0) + hv[2]*bf_lo(p1) + hv[3]*bf_hi(p1);
            }
            g += __shfl_xor(g, 4);            // combine k-halves
            float gb = __shfl_xor(g, 1);      // at gate==0: g=i, gb=f, gc=g, gd=o
            float gc = __shfl_xor(g, 2);
            float gd = __shfl_xor(gb, 2);
            if ((tid & 7) == 0) {
                int ji = (jD >> 5) * 36 + (jD & 31);
                float co = st[cur * 288 + 144 + ji];
                float cn = sig_f(gb) * co + sig_f(g) * tanh_f(gc);
                float hn = sig_f(gd) * tanh_f(cn);
                st[(cur ^ 1) * 288 + 144 + ji] = cn;
                st[(cur ^ 1) * 288 + ji]       = hn;
            }
        }
        __syncthreads();
    }

    // ---- out[b] = h·Wff[0:128] + β_last·XG + bff  (final state in buffer 1) ----
    if (tid < 64) {
        int l0 = (lane >> 5) * 36 + (lane & 31);
        int l1 = (2 + (lane >> 5)) * 36 + (lane & 31);
        float v = st[288 + l0] * wh0 + st[288 + l1] * wh1;
        #pragma unroll
        for (int d = 1; d < 64; d <<= 1) v += __shfl_xor(v, d);
        if (lane == 0) out[blockIdx.x] = v + ytg_last + bffv;
    }
}

extern "C" void kernel_launch(void* const* d_in, const int* in_sizes, int n_in,
                              void* d_out, int out_size, void* d_ws, size_t ws_size,
                              hipStream_t stream) {
    dec_kernel<<<Bsz, NTH, 0, stream>>>(
        (const float*)d_in[0],  (const float*)d_in[1],  (const float*)d_in[2],
        (const float*)d_in[3],  (const float*)d_in[4],  (const float*)d_in[5],
        (const float*)d_in[6],  (const float*)d_in[7],  (const float*)d_in[8],
        (const float*)d_in[9],  (const float*)d_in[10], (const float*)d_in[11],
        (const float*)d_in[12], (const float*)d_in[13], (float*)d_out);
}

// Round 4
// 9774.823 us; speedup vs baseline: 3.1112x; 1.3601x over previous
//
#include <hip/hip_runtime.h>
#include <stdint.h>

#define Bsz   4096
#define STEPS 127
#define NTH   512

typedef float f4v __attribute__((ext_vector_type(4)));

__device__ __forceinline__ float rcp_f(float x) { return __builtin_amdgcn_rcpf(x); }
__device__ __forceinline__ float tanh_f(float x) {
    float p = __expf(2.0f * x);
    return 1.0f - 2.0f * rcp_f(p + 1.0f);
}
__device__ __forceinline__ float sig_f(float x) {
    return rcp_f(1.0f + __expf(-x));
}
__device__ __forceinline__ uint32_t pack_bf2(float a, float b) {
    union { float f; uint32_t u; } ua, ub;
    ua.f = a; ub.f = b;
    uint32_t x = ua.u + (0x7fffu + ((ua.u >> 16) & 1u));
    uint32_t y = ub.u + (0x7fffu + ((ub.u >> 16) & 1u));
    return (x >> 16) | (y & 0xffff0000u);
}
__device__ __forceinline__ float bf_lo(uint32_t p) {
    union { uint32_t u; float f; } v; v.u = p << 16; return v.f;
}
__device__ __forceinline__ float bf_hi(uint32_t p) {
    union { uint32_t u; float f; } v; v.u = p & 0xffff0000u; return v.f;
}

// 512 threads; explicit backend attrs: waves_per_eu(2,4) -> 256-VGPR budget.
// Persistent per thread: whh[64]+w1pk[32] u32 + ep[32] f32 + scalars ~ 180 regs
// -> no spill (R2/R3 failure mode). 1 block/CU (LDS ~81KB), 8 waves/CU.
__global__ __attribute__((amdgpu_flat_work_group_size(NTH, NTH)))
           __attribute__((amdgpu_waves_per_eu(2, 4)))
void dec_kernel(const float* __restrict__ X,    // (B,128,128)
                const float* __restrict__ yh,   // (B,127,1)
                const float* __restrict__ W1,   // (128,384): [:,:128]=W1h [:,128:256]=W1c [:,256:]=W1e
                const float* __restrict__ b1,   // (128)
                const float* __restrict__ W2,   // (1,128)
                const float* __restrict__ b2u,  // (1) softmax-invariant, unused
                const float* __restrict__ Wih,  // (512,1)
                const float* __restrict__ Whh,  // (512,128)
                const float* __restrict__ bih,  // (512)
                const float* __restrict__ bhh,  // (512)
                const float* __restrict__ fcW,  // (1,129)
                const float* __restrict__ fcb,  // (1)
                const float* __restrict__ Wff,  // (1,256)
                const float* __restrict__ bff,  // (1)
                float* __restrict__ out)        // (B,1)
{
    const int tid  = threadIdx.x;
    const int lane = tid & 63;

    __shared__ __align__(16) float EP[128][132];   // enc_proj fp32 (setup only)
    __shared__ __align__(16) float Xt[16][132];    // setup staging, bank-swizzled
    __shared__ __align__(16) float state[2][288];  // concat(h,c) chunk-padded [8][36]
    __shared__ __align__(16) float e_part[512];    // [4][128]
    __shared__ __align__(16) float hc_c[4][36];    // hc chunk-padded
    __shared__ __align__(16) float w2c[4][36];     // w2 chunk-padded
    __shared__ __align__(16) float y_s[STEPS + 1];
    __shared__ __align__(16) float XF[128];
    __shared__ __align__(16) float XG[128];

    const float* Xb = X + (size_t)blockIdx.x * (128 * 128);
    float* st = &state[0][0];

    if (tid < 288)   st[tid] = 0.f;
    if (tid < STEPS) y_s[tid] = yh[(size_t)blockIdx.x * STEPS + tid];
    if (tid < 128)   w2c[tid >> 5][tid & 31] = W2[tid];

    const int jA = tid >> 2;   // 0..127
    const int qA = tid & 3;    // 4 threads per j

    // ---- XF[t]=X[t]·fcW[0:128], XG[t]=X[t]·Wff[128:256] (ctx eliminated) ----
    {
        float aF = 0.f, aG = 0.f;
        #pragma unroll
        for (int u = 0; u < 8; ++u) {
            f4v xv = *(const f4v*)(Xb + jA * 128 + qA * 32 + 4 * u);
            f4v fv = *(const f4v*)(fcW + qA * 32 + 4 * u);
            f4v gv = *(const f4v*)(Wff + 128 + qA * 32 + 4 * u);
            aF += xv[0]*fv[0] + xv[1]*fv[1] + xv[2]*fv[2] + xv[3]*fv[3];
            aG += xv[0]*gv[0] + xv[1]*gv[1] + xv[2]*gv[2] + xv[3]*gv[3];
        }
        aF += __shfl_xor(aF, 1); aF += __shfl_xor(aF, 2);
        aG += __shfl_xor(aG, 1); aG += __shfl_xor(aG, 2);
        if (qA == 0) { XF[jA] = aF; XG[jA] = aG; }
    }

    // ---- enc_proj (one-time fp32): EP[t][j] = X[t]·W1e[j] ----
    {
        float w1e[32];
        #pragma unroll
        for (int u = 0; u < 8; ++u) {
            f4v w = *(const f4v*)(W1 + jA * 384 + 256 + qA * 32 + 4 * u);
            w1e[4*u] = w[0]; w1e[4*u+1] = w[1]; w1e[4*u+2] = w[2]; w1e[4*u+3] = w[3];
        }
        for (int tile = 0; tile < 8; ++tile) {
            __syncthreads();
            {   // stage 16 rows (512 f4, 1/thread); f4 slot c4 -> pos (c4&7)*4+(c4>>3)
                int row = tid >> 5, c4 = tid & 31;
                int p = (c4 & 7) * 4 + (c4 >> 3);
                *(f4v*)&Xt[row][p * 4] = *(const f4v*)(Xb + (tile * 16 + row) * 128 + c4 * 4);
            }
            __syncthreads();
            for (int tl = 0; tl < 16; ++tl) {
                float acc = 0.f;
                #pragma unroll
                for (int u = 0; u < 8; ++u) {      // elems qA*32+4u.. -> slot u*4+qA
                    f4v xv = *(const f4v*)&Xt[tl][(u * 4 + qA) * 4];
                    acc += xv[0]*w1e[4*u] + xv[1]*w1e[4*u+1]
                         + xv[2]*w1e[4*u+2] + xv[3]*w1e[4*u+3];
                }
                acc += __shfl_xor(acc, 1);
                acc += __shfl_xor(acc, 2);
                if (qA == 0) EP[tile * 16 + tl][jA] = acc;
            }
        }
    }
    __syncthreads();

    // ---- EP slice to registers: thread (tB,qB) owns EP[tB][qB*32 .. +32] ----
    const int tB = tid & 127;
    const int qB = tid >> 7;
    float ep[32];
    #pragma unroll
    for (int u = 0; u < 8; ++u) {
        f4v v = *(const f4v*)&EP[tB][qB * 32 + 4 * u];
        ep[4*u] = v[0]; ep[4*u+1] = v[1]; ep[4*u+2] = v[2]; ep[4*u+3] = v[3];
    }

    // ---- persistent weights (bf16-packed) ----
    uint32_t w1pk[32];   // concat(W1h,W1c)[jA], elems qA*64 .. +64 (contiguous in W1 row)
    #pragma unroll
    for (int m = 0; m < 16; ++m) {
        f4v a = *(const f4v*)(W1 + jA * 384 + qA * 64 + 4 * m);
        w1pk[2*m]   = pack_bf2(a[0], a[1]);
        w1pk[2*m+1] = pack_bf2(a[2], a[3]);
    }
    const int jD = tid >> 2;                 // cell 0..127
    const int r  = (tid & 3) * 128 + jD;     // gate row: quad lane q owns gate q
    uint32_t whh[64];                        // Whh[r][:], in state-chunk order
    #pragma unroll
    for (int m = 0; m < 32; ++m) {
        int ge = (m >> 3) * 32 + (m & 7) * 4;
        f4v w = *(const f4v*)(Whh + (size_t)r * 128 + ge);
        whh[2*m]   = pack_bf2(w[0], w[1]);
        whh[2*m+1] = pack_bf2(w[2], w[3]);
    }
    const float wihv = Wih[r];
    const float bgv  = bih[r] + bhh[r];
    const float b1j  = b1[jA];
    const float fcwy = fcW[128];
    const float fcbv = fcb[0];
    const float bffv = bff[0];
    const float wh0  = Wff[lane];
    const float wh1  = Wff[lane + 64];
    float ytg_last = 0.f;
    __syncthreads();

    // ================= scan: 127 steps, 3 barriers each =================
    for (int s = 0; s < STEPS; ++s) {
        const int cur = s & 1;

        // -- A: hc[j] = b1[j] + concat(h,c)·concat(W1h,W1c)[j]  (4 thr/j, 64 elems)
        {
            float acc = 0.f;
            const float* sb0 = st + cur * 288 + qA * 72;       // chunk 2qA
            const float* sb1 = sb0 + 36;                       // chunk 2qA+1
            #pragma unroll
            for (int u = 0; u < 8; ++u) {
                f4v sv = *(const f4v*)(sb0 + 4 * u);
                uint32_t p0 = w1pk[2*u], p1 = w1pk[2*u+1];
                acc += sv[0]*bf_lo(p0) + sv[1]*bf_hi(p0) + sv[2]*bf_lo(p1) + sv[3]*bf_hi(p1);
            }
            #pragma unroll
            for (int u = 0; u < 8; ++u) {
                f4v sv = *(const f4v*)(sb1 + 4 * u);
                uint32_t p0 = w1pk[16 + 2*u], p1 = w1pk[16 + 2*u+1];
                acc += sv[0]*bf_lo(p0) + sv[1]*bf_hi(p0) + sv[2]*bf_lo(p1) + sv[3]*bf_hi(p1);
            }
            acc += __shfl_xor(acc, 1);
            acc += __shfl_xor(acc, 2);
            if (qA == 0) hc_c[jA >> 5][jA & 31] = acc + b1j;
        }
        __syncthreads();

        // -- B: e_part[qB][tB] = Σ_{h in 32-chunk} w2[h]·tanh(ep[h]+hc[h])
        {
            float acc = 0.f;
            #pragma unroll
            for (int u = 0; u < 8; ++u) {
                f4v hcv = *(const f4v*)&hc_c[qB][4 * u];
                f4v w2v = *(const f4v*)&w2c[qB][4 * u];
                #pragma unroll
                for (int k = 0; k < 4; ++k)
                    acc += w2v[k] * tanh_f(ep[4*u + k] + hcv[k]);
            }
            e_part[qB * 128 + tB] = acc;
        }
        __syncthreads();

        // -- S: redundant per-wave softmax + fused β·XF / β·XG (no barrier after)
        float ytc;
        {
            float v0 = e_part[lane]       + e_part[128 + lane]
                     + e_part[256 + lane] + e_part[384 + lane];
            float v1 = e_part[64 + lane]  + e_part[192 + lane]
                     + e_part[320 + lane] + e_part[448 + lane];
            float m = fmaxf(v0, v1);
            #pragma unroll
            for (int d = 1; d < 64; d <<= 1) m = fmaxf(m, __shfl_xor(m, d));
            float p0 = __expf(v0 - m), p1 = __expf(v1 - m);
            float sp = p0 + p1;
            float sf = p0 * XF[lane] + p1 * XF[lane + 64];
            float sg = p0 * XG[lane] + p1 * XG[lane + 64];
            #pragma unroll
            for (int d = 1; d < 64; d <<= 1) {
                sp += __shfl_xor(sp, d);
                sf += __shfl_xor(sf, d);
                sg += __shfl_xor(sg, d);
            }
            float inv = rcp_f(sp);
            ytc      = sf * inv;
            ytg_last = sg * inv;
        }

        // -- D: full gate row dot (1 thr/row); LSTM update fused via quad shuffles
        {
            float ytilde = ytc + fcwy * y_s[s] + fcbv;
            float g = bgv + wihv * ytilde;
            const float* hb = st + cur * 288;
            #pragma unroll
            for (int m = 0; m < 32; ++m) {
                f4v hv = *(const f4v*)(hb + (m >> 3) * 36 + (m & 7) * 4);
                uint32_t p0 = whh[2*m], p1 = whh[2*m+1];
                g += hv[0]*bf_lo(p0) + hv[1]*bf_hi(p0) + hv[2]*bf_lo(p1) + hv[3]*bf_hi(p1);
            }
            float gb = __shfl_xor(g, 1);   // at quad lane 0: g=i, gb=f, gc=g, gd=o
            float gc = __shfl_xor(g, 2);
            float gd = __shfl_xor(gb, 2);
            if ((tid & 3) == 0) {
                int ji = (jD >> 5) * 36 + (jD & 31);
                float co = st[cur * 288 + 144 + ji];
                float cn = sig_f(gb) * co + sig_f(g) * tanh_f(gc);
                float hn = sig_f(gd) * tanh_f(cn);
                st[(cur ^ 1) * 288 + 144 + ji] = cn;
                st[(cur ^ 1) * 288 + ji]       = hn;
            }
        }
        __syncthreads();
    }

    // ---- out[b] = h·Wff[0:128] + β_last·XG + bff  (final state in buffer 1) ----
    if (tid < 64) {
        int l0 = (lane >> 5) * 36 + (lane & 31);
        int l1 = (2 + (lane >> 5)) * 36 + (lane & 31);
        float v = st[288 + l0] * wh0 + st[288 + l1] * wh1;
        #pragma unroll
        for (int d = 1; d < 64; d <<= 1) v += __shfl_xor(v, d);
        if (lane == 0) out[blockIdx.x] = v + ytg_last + bffv;
    }
}

extern "C" void kernel_launch(void* const* d_in, const int* in_sizes, int n_in,
                              void* d_out, int out_size, void* d_ws, size_t ws_size,
                              hipStream_t stream) {
    dec_kernel<<<Bsz, NTH, 0, stream>>>(
        (const float*)d_in[0],  (const float*)d_in[1],  (const float*)d_in[2],
        (const float*)d_in[3],  (const float*)d_in[4],  (const float*)d_in[5],
        (const float*)d_in[6],  (const float*)d_in[7],  (const float*)d_in[8],
        (const float*)d_in[9],  (const float*)d_in[10], (const float*)d_in[11],
        (const float*)d_in[12], (const float*)d_in[13], (float*)d_out);
}

// Round 6
// 6529.907 us; speedup vs baseline: 4.6573x; 1.4969x over previous
//
#include <hip/hip_runtime.h>
#include <stdint.h>

#define Bsz   4096
#define STEPS 127
#define NTH   512

typedef float    f4v __attribute__((ext_vector_type(4)));
typedef uint32_t u4v __attribute__((ext_vector_type(4)));
typedef _Float16 h2v __attribute__((ext_vector_type(2)));
typedef __fp16   g2v __attribute__((ext_vector_type(2)));

#define K2E  1.4426950408889634f
#define K2E2 2.8853900817779268f

__device__ __forceinline__ float rcp_f(float x) { return __builtin_amdgcn_rcpf(x); }
__device__ __forceinline__ float exp2_f(float x) {
#if __has_builtin(__builtin_amdgcn_exp2f)
    return __builtin_amdgcn_exp2f(x);
#else
    return exp2f(x);
#endif
}
__device__ __forceinline__ float sig_f(float x)  { return rcp_f(1.f + exp2_f(-K2E * x)); }
__device__ __forceinline__ float tanh_f(float x) { return 1.f - 2.f * rcp_f(1.f + exp2_f(K2E2 * x)); }
__device__ __forceinline__ uint32_t pkh2(float a, float b) {
    union { uint32_t u; g2v h; } v;
    v.h = __builtin_amdgcn_cvt_pkrtz(a, b);
    return v.u;
}
__device__ __forceinline__ float dot2(uint32_t a, uint32_t b, float c) {
    union { uint32_t u; h2v h; } x, y;
    x.u = a; y.u = b;
#if __has_builtin(__builtin_amdgcn_fdot2)
    return __builtin_amdgcn_fdot2(x.h, y.h, c, false);
#else
    return c + (float)x.h[0] * (float)y.h[0] + (float)x.h[1] * (float)y.h[1];
#endif
}

// 512 thr, cap 128 VGPR (empirical: launch_bounds(512,2)). Persistent regs:
// whh[64]+w1pk[32]+~8 scalars ~104 -> NO spill. LDS 79.2KB -> 2 blocks/CU.
__global__ __launch_bounds__(NTH, 2)
void dec_kernel(const float* __restrict__ X,    // (B,128,128)
                const float* __restrict__ yh,   // (B,127,1)
                const float* __restrict__ W1,   // (128,384)
                const float* __restrict__ b1,   // (128)
                const float* __restrict__ W2,   // (1,128)
                const float* __restrict__ b2u,  // (1) softmax-invariant
                const float* __restrict__ Wih,  // (512,1)
                const float* __restrict__ Whh,  // (512,128)
                const float* __restrict__ bih,  // (512)
                const float* __restrict__ bhh,  // (512)
                const float* __restrict__ fcW,  // (1,129)
                const float* __restrict__ fcb,  // (1)
                const float* __restrict__ Wff,  // (1,256)
                const float* __restrict__ bff,  // (1)
                float* __restrict__ out)        // (B,1)
{
    const int tid  = threadIdx.x;
    const int lane = tid & 63;

    __shared__ __align__(16) float    EPT[128][132];  // K2E2 * enc_proj, TRANSPOSED [j][t]
    __shared__ __align__(16) float    Xt[8][132];     // setup staging
    __shared__ __align__(16) uint32_t st2[2][144];    // half2 pairs of concat(h,c), [4 chunks][36]
    __shared__ __align__(16) float    c32[2][128];    // c carry, fp32
    __shared__ __align__(16) float    h32[128];       // h fp32 (final readout)
    __shared__ __align__(16) float    e_part[512];
    __shared__ __align__(16) float    hc2c[4][36];    // K2E2*(hc+b1), chunk-padded
    __shared__ __align__(16) float    w2m[4][36];     // -2*w2, chunk-padded
    __shared__ __align__(16) float    y_s[STEPS + 1]; // prescaled fcwy*y + fcb
    __shared__ __align__(16) float    XF[128];
    __shared__ __align__(16) float    XG[128];

    const float* Xb = X + (size_t)blockIdx.x * (128 * 128);

    if (tid < 288)   ((uint32_t*)st2)[tid] = 0u;
    if (tid < 128)   c32[0][tid] = 0.f;
    if (tid < STEPS) y_s[tid] = fcW[128] * yh[(size_t)blockIdx.x * STEPS + tid] + fcb[0];
    if (tid < 128)   w2m[tid >> 5][tid & 31] = -2.f * W2[tid];

    const int jA = tid >> 2;   // 0..127
    const int qA = tid & 3;    // 4 threads per j

    // ---- XF[t]=X[t]·fcW[0:128], XG[t]=X[t]·Wff[128:256] (ctx eliminated) ----
    {
        float aF = 0.f, aG = 0.f;
        #pragma unroll
        for (int u = 0; u < 8; ++u) {
            f4v xv = *(const f4v*)(Xb + jA * 128 + qA * 32 + 4 * u);
            f4v fv = *(const f4v*)(fcW + qA * 32 + 4 * u);
            f4v gv = *(const f4v*)(Wff + 128 + qA * 32 + 4 * u);
            aF += xv[0]*fv[0] + xv[1]*fv[1] + xv[2]*fv[2] + xv[3]*fv[3];
            aG += xv[0]*gv[0] + xv[1]*gv[1] + xv[2]*gv[2] + xv[3]*gv[3];
        }
        aF += __shfl_xor(aF, 1); aF += __shfl_xor(aF, 2);
        aG += __shfl_xor(aG, 1); aG += __shfl_xor(aG, 2);
        if (qA == 0) { XF[jA] = aF; XG[jA] = aG; }
    }

    // ---- enc_proj one-time fp32: EPT[j][t] = K2E2 * X[t]·W1e[j] ----
    {
        float w1e[32];
        #pragma unroll
        for (int u = 0; u < 8; ++u) {
            f4v w = *(const f4v*)(W1 + jA * 384 + 256 + qA * 32 + 4 * u);
            w1e[4*u] = w[0]; w1e[4*u+1] = w[1]; w1e[4*u+2] = w[2]; w1e[4*u+3] = w[3];
        }
        for (int tile = 0; tile < 16; ++tile) {
            __syncthreads();
            if (tid < 256) {   // stage 8 rows; f4 slot c4 -> (c4&7)*4+(c4>>3) (broadcast reads)
                int row = tid >> 5, c4 = tid & 31;
                int p = (c4 & 7) * 4 + (c4 >> 3);
                *(f4v*)&Xt[row][p * 4] = *(const f4v*)(Xb + (tile * 8 + row) * 128 + c4 * 4);
            }
            __syncthreads();
            #pragma unroll
            for (int tl = 0; tl < 8; ++tl) {
                float acc = 0.f;
                #pragma unroll
                for (int u = 0; u < 8; ++u) {
                    f4v xv = *(const f4v*)&Xt[tl][(u * 4 + qA) * 4];
                    acc += xv[0]*w1e[4*u] + xv[1]*w1e[4*u+1]
                         + xv[2]*w1e[4*u+2] + xv[3]*w1e[4*u+3];
                }
                acc += __shfl_xor(acc, 1);
                acc += __shfl_xor(acc, 2);
                if (qA == 0) EPT[jA][tile * 8 + tl] = K2E2 * acc;
            }
        }
    }

    // ---- persistent weights (fp16-pair packed) ----
    uint32_t w1pk[32];   // concat(W1h,W1c)[jA], pairs qA*32..+32 (elems qA*64..+64)
    #pragma unroll
    for (int m = 0; m < 16; ++m) {
        f4v a = *(const f4v*)(W1 + jA * 384 + qA * 64 + 4 * m);
        w1pk[2*m]   = pkh2(a[0], a[1]);
        w1pk[2*m+1] = pkh2(a[2], a[3]);
    }
    const int jD = tid >> 2;               // cell
    const int r  = (tid & 3) * 128 + jD;   // gate row (quad lane q = gate q)
    uint32_t whh[64];                      // Whh[r][:] as 64 h2 pairs
    #pragma unroll
    for (int m = 0; m < 32; ++m) {
        f4v w = *(const f4v*)(Whh + (size_t)r * 128 + 4 * m);
        whh[2*m]   = pkh2(w[0], w[1]);
        whh[2*m+1] = pkh2(w[2], w[3]);
    }
    const float wihv = Wih[r];
    const float bgv  = bih[r] + bhh[r];
    const float b1s  = K2E2 * b1[jA];
    const int   tB   = tid & 127;
    const int   qB   = tid >> 7;
    float ytg_last = 0.f;
    __syncthreads();

    // ================= scan: 127 steps, 3 barriers each =================
    for (int s = 0; s < STEPS; ++s) {
        const int cur = s & 1;

        // -- A: hc2[j] = K2E2*(concat(h,c)·W1row[j] + b1[j])  (4 thr/j, dot2)
        {
            float a0 = 0.f, a1 = 0.f;
            const uint32_t* sb = &st2[cur][qA * 36];
            #pragma unroll
            for (int u = 0; u < 8; ++u) {
                u4v sv = *(const u4v*)(sb + 4 * u);
                a0 = dot2(sv[0], w1pk[4*u],   a0);
                a1 = dot2(sv[1], w1pk[4*u+1], a1);
                a0 = dot2(sv[2], w1pk[4*u+2], a0);
                a1 = dot2(sv[3], w1pk[4*u+3], a1);
            }
            float acc = a0 + a1;
            acc += __shfl_xor(acc, 1);
            acc += __shfl_xor(acc, 2);
            if (qA == 0) hc2c[jA >> 5][jA & 31] = fmaf(K2E2, acc, b1s);
        }
        __syncthreads();

        // -- B: e_part += -2*w2[h]*rcp(1+exp2(ept+hc2))   (Σw2 const cancels in softmax)
        {
            const float* epb = &EPT[qB * 32][tB];
            float x0 = 0.f, x1 = 0.f, x2 = 0.f, x3 = 0.f;
            #pragma unroll
            for (int u = 0; u < 8; ++u) {
                f4v hcv = *(const f4v*)&hc2c[qB][4 * u];
                f4v wv  = *(const f4v*)&w2m[qB][4 * u];
                float z0 = exp2_f(epb[(4*u+0) * 132] + hcv[0]);
                float z1 = exp2_f(epb[(4*u+1) * 132] + hcv[1]);
                float z2 = exp2_f(epb[(4*u+2) * 132] + hcv[2]);
                float z3 = exp2_f(epb[(4*u+3) * 132] + hcv[3]);
                x0 = fmaf(wv[0], rcp_f(1.f + z0), x0);
                x1 = fmaf(wv[1], rcp_f(1.f + z1), x1);
                x2 = fmaf(wv[2], rcp_f(1.f + z2), x2);
                x3 = fmaf(wv[3], rcp_f(1.f + z3), x3);
            }
            e_part[qB * 128 + tB] = (x0 + x1) + (x2 + x3);
        }
        __syncthreads();

        // -- S: per-wave redundant softmax + fused β·XF / β·XG (no barrier)
        float ytc;
        {
            float v0 = e_part[lane]      + e_part[128 + lane]
                     + e_part[256 + lane] + e_part[384 + lane];
            float v1 = e_part[64 + lane] + e_part[192 + lane]
                     + e_part[320 + lane] + e_part[448 + lane];
            float m = fmaxf(v0, v1);
            #pragma unroll
            for (int d = 1; d < 64; d <<= 1) m = fmaxf(m, __shfl_xor(m, d));
            float p0 = exp2_f(K2E * (v0 - m)), p1 = exp2_f(K2E * (v1 - m));
            float sp = p0 + p1;
            float sf = p0 * XF[lane] + p1 * XF[lane + 64];
            float sg = p0 * XG[lane] + p1 * XG[lane + 64];
            #pragma unroll
            for (int d = 1; d < 64; d <<= 1) {
                sp += __shfl_xor(sp, d);
                sf += __shfl_xor(sf, d);
                sg += __shfl_xor(sg, d);
            }
            float inv = rcp_f(sp);
            ytc      = sf * inv;
            ytg_last = sg * inv;
        }

        // -- D: gate row dot via dot2; E fused via quad shuffles
        {
            float yt = ytc + y_s[s];
            float d0 = 0.f, d1 = 0.f, d2 = 0.f, d3 = fmaf(wihv, yt, bgv);
            const uint32_t* hb = &st2[cur][0];
            #pragma unroll
            for (int m = 0; m < 8; ++m) {          // h pairs 0..31 (chunk 0)
                u4v sv = *(const u4v*)(hb + 4 * m);
                d0 = dot2(sv[0], whh[4*m],   d0);
                d1 = dot2(sv[1], whh[4*m+1], d1);
                d2 = dot2(sv[2], whh[4*m+2], d2);
                d3 = dot2(sv[3], whh[4*m+3], d3);
            }
            #pragma unroll
            for (int m = 0; m < 8; ++m) {          // h pairs 32..63 (chunk 1, slot +36)
                u4v sv = *(const u4v*)(hb + 36 + 4 * m);
                d0 = dot2(sv[0], whh[32 + 4*m],   d0);
                d1 = dot2(sv[1], whh[32 + 4*m+1], d1);
                d2 = dot2(sv[2], whh[32 + 4*m+2], d2);
                d3 = dot2(sv[3], whh[32 + 4*m+3], d3);
            }
            float g  = (d0 + d1) + (d2 + d3);
            float gb = __shfl_xor(g, 1);   // at quad lane 0: g=i, gb=f, gc=g, gd=o
            float gc = __shfl_xor(g, 2);
            float gd = __shfl_xor(gb, 2);
            if ((tid & 3) == 0) {
                float co = c32[cur][jD];
                float cn = sig_f(gb) * co + sig_f(g) * tanh_f(gc);
                float hn = sig_f(gd) * tanh_f(cn);
                c32[cur ^ 1][jD] = cn;
                h32[jD] = hn;
                float hp = __shfl_xor(hn, 4);      // partner cell (all %4==0 lanes active)
                float cp = __shfl_xor(cn, 4);
                if ((tid & 7) == 0) {
                    int m0 = tid >> 3;             // pair index 0..63
                    int sl = m0 + 4 * (m0 >> 5);   // chunk-padded slot
                    st2[cur ^ 1][sl]      = pkh2(hn, hp);
                    st2[cur ^ 1][72 + sl] = pkh2(cn, cp);
                }
            }
        }
        __syncthreads();
    }

    // ---- out[b] = h·Wff[0:128] + β_last·XG + bff ----
    if (tid < 64) {
        float v = h32[lane] * Wff[lane] + h32[lane + 64] * Wff[lane + 64];
        #pragma unroll
        for (int d = 1; d < 64; d <<= 1) v += __shfl_xor(v, d);
        if (lane == 0) out[blockIdx.x] = v + ytg_last + bff[0];
    }
}

extern "C" void kernel_launch(void* const* d_in, const int* in_sizes, int n_in,
                              void* d_out, int out_size, void* d_ws, size_t ws_size,
                              hipStream_t stream) {
    dec_kernel<<<Bsz, NTH, 0, stream>>>(
        (const float*)d_in[0],  (const float*)d_in[1],  (const float*)d_in[2],
        (const float*)d_in[3],  (const float*)d_in[4],  (const float*)d_in[5],
        (const float*)d_in[6],  (const float*)d_in[7],  (const float*)d_in[8],
        (const float*)d_in[9],  (const float*)d_in[10], (const float*)d_in[11],
        (const float*)d_in[12], (const float*)d_in[13], (float*)d_out);
}

// Round 7
// 6028.553 us; speedup vs baseline: 5.0446x; 1.0832x over previous
//
#include <hip/hip_runtime.h>
#include <stdint.h>

#define Bsz   4096
#define STEPS 127
#define NTH   512

typedef float    f4v __attribute__((ext_vector_type(4)));
typedef uint32_t u4v __attribute__((ext_vector_type(4)));
typedef _Float16 h2v __attribute__((ext_vector_type(2)));
typedef __fp16   g2v __attribute__((ext_vector_type(2)));

#define K2E  1.4426950408889634f
#define K2E2 2.8853900817779268f

__device__ __forceinline__ float rcp_f(float x) { return __builtin_amdgcn_rcpf(x); }
__device__ __forceinline__ float exp2_f(float x) {
#if __has_builtin(__builtin_amdgcn_exp2f)
    return __builtin_amdgcn_exp2f(x);
#else
    return exp2f(x);
#endif
}
__device__ __forceinline__ float sig_f(float x)  { return rcp_f(1.f + exp2_f(-K2E * x)); }
__device__ __forceinline__ float tanh_f(float x) { return 1.f - 2.f * rcp_f(1.f + exp2_f(K2E2 * x)); }
__device__ __forceinline__ uint32_t pkh2(float a, float b) {
    union { uint32_t u; g2v h; } v;
    v.h = __builtin_amdgcn_cvt_pkrtz(a, b);
    return v.u;
}
__device__ __forceinline__ float h2lo(uint32_t p) {
    union { uint32_t u; h2v h; } v; v.u = p; return (float)v.h[0];
}
__device__ __forceinline__ float h2hi(uint32_t p) {
    union { uint32_t u; h2v h; } v; v.u = p; return (float)v.h[1];
}
__device__ __forceinline__ float dot2(uint32_t a, uint32_t b, float c) {
    union { uint32_t u; h2v h; } x, y;
    x.u = a; y.u = b;
#if __has_builtin(__builtin_amdgcn_fdot2)
    return __builtin_amdgcn_fdot2(x.h, y.h, c, false);
#else
    return c + (float)x.h[0] * (float)y.h[0] + (float)x.h[1] * (float)y.h[1];
#endif
}

// 512 thr, VGPR cap 128 (launch_bounds(512,2) empirical). LDS ~44KB so TWO
// blocks/CU co-resident with huge margin (R6's 79KB mysteriously got only 1).
__global__ __launch_bounds__(NTH, 2)
void dec_kernel(const float* __restrict__ X,    // (B,128,128)
                const float* __restrict__ yh,   // (B,127,1)
                const float* __restrict__ W1,   // (128,384)
                const float* __restrict__ b1,   // (128)
                const float* __restrict__ W2,   // (1,128)
                const float* __restrict__ b2u,  // (1) softmax-invariant
                const float* __restrict__ Wih,  // (512,1)
                const float* __restrict__ Whh,  // (512,128)
                const float* __restrict__ bih,  // (512)
                const float* __restrict__ bhh,  // (512)
                const float* __restrict__ fcW,  // (1,129)
                const float* __restrict__ fcb,  // (1)
                const float* __restrict__ Wff,  // (1,256)
                const float* __restrict__ bff,  // (1)
                float* __restrict__ out)        // (B,1)
{
    const int tid  = threadIdx.x;
    const int lane = tid & 63;

    __shared__ __align__(16) uint32_t EPT_pk[64][133]; // enc_proj fp16 pairs over j, [jp][t]
    __shared__ __align__(16) float    Xt[8][132];      // setup staging
    __shared__ __align__(16) uint32_t st2[2][144];     // half2 pairs of concat(h,c), [4 chunks][36]
    __shared__ __align__(16) float    c32[2][128];     // c carry, fp32
    __shared__ __align__(16) float    h32[128];        // h fp32 (final readout)
    __shared__ __align__(16) float    e_s[128];        // logits
    __shared__ __align__(16) float    hc2c[4][36];     // K2E2*(hc+b1), chunk-padded
    __shared__ __align__(16) float    w2m[4][36];      // -2*w2, chunk-padded
    __shared__ __align__(16) float    y_s[STEPS + 1];  // prescaled fcwy*y + fcb
    __shared__ __align__(16) float    XF[128];
    __shared__ __align__(16) float    XG[128];

    const float* Xb = X + (size_t)blockIdx.x * (128 * 128);

    if (tid < 288)   ((uint32_t*)st2)[tid] = 0u;
    if (tid < 128)   c32[0][tid] = 0.f;
    if (tid < STEPS) y_s[tid] = fcW[128] * yh[(size_t)blockIdx.x * STEPS + tid] + fcb[0];
    if (tid < 128)   w2m[tid >> 5][tid & 31] = -2.f * W2[tid];

    const int jA = tid >> 2;   // 0..127
    const int qA = tid & 3;    // 4 threads per j

    // ---- XF[t]=X[t]·fcW[0:128], XG[t]=X[t]·Wff[128:256] (ctx eliminated) ----
    {
        float aF = 0.f, aG = 0.f;
        #pragma unroll
        for (int u = 0; u < 8; ++u) {
            f4v xv = *(const f4v*)(Xb + jA * 128 + qA * 32 + 4 * u);
            f4v fv = *(const f4v*)(fcW + qA * 32 + 4 * u);
            f4v gv = *(const f4v*)(Wff + 128 + qA * 32 + 4 * u);
            aF += xv[0]*fv[0] + xv[1]*fv[1] + xv[2]*fv[2] + xv[3]*fv[3];
            aG += xv[0]*gv[0] + xv[1]*gv[1] + xv[2]*gv[2] + xv[3]*gv[3];
        }
        aF += __shfl_xor(aF, 1); aF += __shfl_xor(aF, 2);
        aG += __shfl_xor(aG, 1); aG += __shfl_xor(aG, 2);
        if (qA == 0) { XF[jA] = aF; XG[jA] = aG; }
    }

    // ---- enc_proj one-time fp32 math, fp16-pair store: EPT_pk[j/2][t] ----
    {
        float w1e[32];
        #pragma unroll
        for (int u = 0; u < 8; ++u) {
            f4v w = *(const f4v*)(W1 + jA * 384 + 256 + qA * 32 + 4 * u);
            w1e[4*u] = w[0]; w1e[4*u+1] = w[1]; w1e[4*u+2] = w[2]; w1e[4*u+3] = w[3];
        }
        for (int tile = 0; tile < 16; ++tile) {
            __syncthreads();
            if (tid < 256) {   // stage 8 rows; f4 slot c4 -> (c4&7)*4+(c4>>3) (broadcast reads)
                int row = tid >> 5, c4 = tid & 31;
                int p = (c4 & 7) * 4 + (c4 >> 3);
                *(f4v*)&Xt[row][p * 4] = *(const f4v*)(Xb + (tile * 8 + row) * 128 + c4 * 4);
            }
            __syncthreads();
            #pragma unroll
            for (int tl = 0; tl < 8; ++tl) {
                float acc = 0.f;
                #pragma unroll
                for (int u = 0; u < 8; ++u) {
                    f4v xv = *(const f4v*)&Xt[tl][(u * 4 + qA) * 4];
                    acc += xv[0]*w1e[4*u] + xv[1]*w1e[4*u+1]
                         + xv[2]*w1e[4*u+2] + xv[3]*w1e[4*u+3];
                }
                acc += __shfl_xor(acc, 1);   // full quad reduce (all quad lanes hold acc)
                acc += __shfl_xor(acc, 2);
                float accp = __shfl_xor(acc, 4);          // partner j's value
                if ((tid & 7) == 0)
                    EPT_pk[tid >> 3][tile * 8 + tl] = pkh2(acc, accp);
            }
        }
    }

    // ---- persistent weights (fp16-pair packed) ----
    uint32_t w1pk[32];   // concat(W1h,W1c)[jA], pairs qA*32..+32 (elems qA*64..+64)
    #pragma unroll
    for (int m = 0; m < 16; ++m) {
        f4v a = *(const f4v*)(W1 + jA * 384 + qA * 64 + 4 * m);
        w1pk[2*m]   = pkh2(a[0], a[1]);
        w1pk[2*m+1] = pkh2(a[2], a[3]);
    }
    const int jD = tid >> 2;               // cell
    const int r  = (tid & 3) * 128 + jD;   // gate row (quad lane q = gate q)
    uint32_t whh[64];                      // Whh[r][:] as 64 h2 pairs
    #pragma unroll
    for (int m = 0; m < 32; ++m) {
        f4v w = *(const f4v*)(Whh + (size_t)r * 128 + 4 * m);
        whh[2*m]   = pkh2(w[0], w[1]);
        whh[2*m+1] = pkh2(w[2], w[3]);
    }
    const float wihv = Wih[r];
    const float bgv  = bih[r] + bhh[r];
    const float b1s  = K2E2 * b1[jA];
    float ytg_last = 0.f;
    __syncthreads();

    // ================= scan: 127 steps, 3 barriers each =================
    for (int s = 0; s < STEPS; ++s) {
        const int cur = s & 1;

        // -- A: hc2[j] = K2E2*(concat(h,c)·W1row[j] + b1[j])  (4 thr/j, dot2)
        {
            float a0 = 0.f, a1 = 0.f;
            const uint32_t* sb = &st2[cur][qA * 36];
            #pragma unroll
            for (int u = 0; u < 8; ++u) {
                u4v sv = *(const u4v*)(sb + 4 * u);
                a0 = dot2(sv[0], w1pk[4*u],   a0);
                a1 = dot2(sv[1], w1pk[4*u+1], a1);
                a0 = dot2(sv[2], w1pk[4*u+2], a0);
                a1 = dot2(sv[3], w1pk[4*u+3], a1);
            }
            float acc = a0 + a1;
            acc += __shfl_xor(acc, 1);
            acc += __shfl_xor(acc, 2);
            if (qA == 0) hc2c[jA >> 5][jA & 31] = fmaf(K2E2, acc, b1s);
        }
        __syncthreads();

        // -- B: quad-per-t logits: e[t] = Σ_h -2*w2[h]*rcp(1+exp2(K2E2*ep+hc2))
        {
            const int t = tid >> 2, q = tid & 3;      // 4 lanes/t, 32 h each
            const uint32_t* ec = &EPT_pk[q * 16][t];  // column t, rows q*16..+16 (stride 133)
            float acc = 0.f;
            #pragma unroll
            for (int u = 0; u < 4; ++u) {
                f4v hcv = *(const f4v*)&hc2c[q][8 * u];
                f4v hcw = *(const f4v*)&hc2c[q][8 * u + 4];
                f4v wv  = *(const f4v*)&w2m[q][8 * u];
                f4v wvw = *(const f4v*)&w2m[q][8 * u + 4];
                #pragma unroll
                for (int k = 0; k < 4; ++k) {
                    uint32_t ep = ec[(4 * u + k) * 133];
                    float hl = (k < 2) ? ((f4v)hcv)[2*k]   : ((f4v)hcw)[2*k-4];
                    float hh = (k < 2) ? ((f4v)hcv)[2*k+1] : ((f4v)hcw)[2*k-3];
                    float wl = (k < 2) ? ((f4v)wv)[2*k]    : ((f4v)wvw)[2*k-4];
                    float wh = (k < 2) ? ((f4v)wv)[2*k+1]  : ((f4v)wvw)[2*k-3];
                    float z0 = exp2_f(fmaf(h2lo(ep), K2E2, hl));
                    float z1 = exp2_f(fmaf(h2hi(ep), K2E2, hh));
                    acc = fmaf(wl, rcp_f(1.f + z0), acc);
                    acc = fmaf(wh, rcp_f(1.f + z1), acc);
                }
            }
            acc += __shfl_xor(acc, 1);
            acc += __shfl_xor(acc, 2);
            if (q == 0) e_s[t] = acc;
        }
        __syncthreads();

        // -- S: per-wave redundant softmax, NO max pass (|e|<=2*sum|w2|~10, fp32-safe)
        float ytc;
        {
            float v0 = e_s[lane], v1 = e_s[lane + 64];
            float p0 = exp2_f(K2E * v0), p1 = exp2_f(K2E * v1);
            float sp = p0 + p1;
            float sf = p0 * XF[lane] + p1 * XF[lane + 64];
            float sg = p0 * XG[lane] + p1 * XG[lane + 64];
            #pragma unroll
            for (int d = 1; d < 64; d <<= 1) {
                sp += __shfl_xor(sp, d);
                sf += __shfl_xor(sf, d);
                sg += __shfl_xor(sg, d);
            }
            float inv = rcp_f(sp);
            ytc      = sf * inv;
            ytg_last = sg * inv;
        }

        // -- D: gate row dot via dot2; LSTM update fused via quad shuffles
        {
            float yt = ytc + y_s[s];
            float d0 = 0.f, d1 = 0.f, d2 = 0.f, d3 = fmaf(wihv, yt, bgv);
            const uint32_t* hb = &st2[cur][0];
            #pragma unroll
            for (int m = 0; m < 8; ++m) {          // h pairs 0..31 (chunk 0)
                u4v sv = *(const u4v*)(hb + 4 * m);
                d0 = dot2(sv[0], whh[4*m],   d0);
                d1 = dot2(sv[1], whh[4*m+1], d1);
                d2 = dot2(sv[2], whh[4*m+2], d2);
                d3 = dot2(sv[3], whh[4*m+3], d3);
            }
            #pragma unroll
            for (int m = 0; m < 8; ++m) {          // h pairs 32..63 (chunk 1, slot +36)
                u4v sv = *(const u4v*)(hb + 36 + 4 * m);
                d0 = dot2(sv[0], whh[32 + 4*m],   d0);
                d1 = dot2(sv[1], whh[32 + 4*m+1], d1);
                d2 = dot2(sv[2], whh[32 + 4*m+2], d2);
                d3 = dot2(sv[3], whh[32 + 4*m+3], d3);
            }
            float g  = (d0 + d1) + (d2 + d3);
            float gb = __shfl_xor(g, 1);   // at quad lane 0: g=i, gb=f, gc=g, gd=o
            float gc = __shfl_xor(g, 2);
            float gd = __shfl_xor(gb, 2);
            if ((tid & 3) == 0) {
                float co = c32[cur][jD];
                float cn = sig_f(gb) * co + sig_f(g) * tanh_f(gc);
                float hn = sig_f(gd) * tanh_f(cn);
                c32[cur ^ 1][jD] = cn;
                h32[jD] = hn;
                float hp = __shfl_xor(hn, 4);      // partner cell
                float cp = __shfl_xor(cn, 4);
                if ((tid & 7) == 0) {
                    int m0 = tid >> 3;             // pair index 0..63
                    int sl = m0 + 4 * (m0 >> 5);   // chunk-padded slot
                    st2[cur ^ 1][sl]      = pkh2(hn, hp);
                    st2[cur ^ 1][72 + sl] = pkh2(cn, cp);
                }
            }
        }
        __syncthreads();
    }

    // ---- out[b] = h·Wff[0:128] + β_last·XG + bff ----
    if (tid < 64) {
        float v = h32[lane] * Wff[lane] + h32[lane + 64] * Wff[lane + 64];
        #pragma unroll
        for (int d = 1; d < 64; d <<= 1) v += __shfl_xor(v, d);
        if (lane == 0) out[blockIdx.x] = v + ytg_last + bff[0];
    }
}

extern "C" void kernel_launch(void* const* d_in, const int* in_sizes, int n_in,
                              void* d_out, int out_size, void* d_ws, size_t ws_size,
                              hipStream_t stream) {
    dec_kernel<<<Bsz, NTH, 0, stream>>>(
        (const float*)d_in[0],  (const float*)d_in[1],  (const float*)d_in[2],
        (const float*)d_in[3],  (const float*)d_in[4],  (const float*)d_in[5],
        (const float*)d_in[6],  (const float*)d_in[7],  (const float*)d_in[8],
        (const float*)d_in[9],  (const float*)d_in[10], (const float*)d_in[11],
        (const float*)d_in[12], (const float*)d_in[13], (float*)d_out);
}

// Round 8
// 6027.378 us; speedup vs baseline: 5.0456x; 1.0002x over previous
//
#include <hip/hip_runtime.h>
#include <stdint.h>

#define Bsz   4096
#define STEPS 127
#define NTH   512

typedef float    f4v __attribute__((ext_vector_type(4)));
typedef uint32_t u4v __attribute__((ext_vector_type(4)));
typedef _Float16 h2v __attribute__((ext_vector_type(2)));
typedef __fp16   g2v __attribute__((ext_vector_type(2)));

#define K2E  1.4426950408889634f
#define K2E2 2.8853900817779268f

__device__ __forceinline__ float rcp_f(float x) { return __builtin_amdgcn_rcpf(x); }
__device__ __forceinline__ float exp2_f(float x) {
#if __has_builtin(__builtin_amdgcn_exp2f)
    return __builtin_amdgcn_exp2f(x);
#else
    return exp2f(x);
#endif
}
__device__ __forceinline__ float sig_f(float x)  { return rcp_f(1.f + exp2_f(-K2E * x)); }
__device__ __forceinline__ float tanh_f(float x) { return 1.f - 2.f * rcp_f(1.f + exp2_f(K2E2 * x)); }
__device__ __forceinline__ uint32_t pkh2(float a, float b) {
    union { uint32_t u; g2v h; } v;
    v.h = __builtin_amdgcn_cvt_pkrtz(a, b);
    return v.u;
}
__device__ __forceinline__ float h2lo(uint32_t p) {
    union { uint32_t u; h2v h; } v; v.u = p; return (float)v.h[0];
}
__device__ __forceinline__ float h2hi(uint32_t p) {
    union { uint32_t u; h2v h; } v; v.u = p; return (float)v.h[1];
}
__device__ __forceinline__ float dot2(uint32_t a, uint32_t b, float c) {
    union { uint32_t u; h2v h; } x, y;
    x.u = a; y.u = b;
#if __has_builtin(__builtin_amdgcn_fdot2)
    return __builtin_amdgcn_fdot2(x.h, y.h, c, false);
#else
    return c + (float)x.h[0] * (float)y.h[0] + (float)x.h[1] * (float)y.h[1];
#endif
}

// R8 = R7 kernel with residency attrs: flat_wgs(512,512)+waves_per_eu(2,4).
// Empirics: launch_bounds(512,2) pinned occupancy at 8 waves/CU (R1/R6/R7);
// this attr pair gave VGPR<=128 in R4. LDS 44.5KB -> 2 blocks/CU now legal
// on all three resources (LDS 89<=160KB, VGPR 104<=128, waves/EU max 4).
__global__ __attribute__((amdgpu_flat_work_group_size(NTH, NTH)))
           __attribute__((amdgpu_waves_per_eu(2, 4)))
void dec_kernel(const float* __restrict__ X,    // (B,128,128)
                const float* __restrict__ yh,   // (B,127,1)
                const float* __restrict__ W1,   // (128,384)
                const float* __restrict__ b1,   // (128)
                const float* __restrict__ W2,   // (1,128)
                const float* __restrict__ b2u,  // (1) softmax-invariant
                const float* __restrict__ Wih,  // (512,1)
                const float* __restrict__ Whh,  // (512,128)
                const float* __restrict__ bih,  // (512)
                const float* __restrict__ bhh,  // (512)
                const float* __restrict__ fcW,  // (1,129)
                const float* __restrict__ fcb,  // (1)
                const float* __restrict__ Wff,  // (1,256)
                const float* __restrict__ bff,  // (1)
                float* __restrict__ out)        // (B,1)
{
    const int tid  = threadIdx.x;
    const int lane = tid & 63;

    __shared__ __align__(16) uint32_t EPT_pk[64][133]; // enc_proj fp16 pairs over j, [jp][t]
    __shared__ __align__(16) float    Xt[8][132];      // setup staging
    __shared__ __align__(16) uint32_t st2[2][144];     // half2 pairs of concat(h,c), [4 chunks][36]
    __shared__ __align__(16) float    c32[2][128];     // c carry, fp32
    __shared__ __align__(16) float    h32[128];        // h fp32 (final readout)
    __shared__ __align__(16) float    e_s[128];        // logits
    __shared__ __align__(16) float    hc2c[4][36];     // K2E2*(hc+b1), chunk-padded
    __shared__ __align__(16) float    w2m[4][36];      // -2*w2, chunk-padded
    __shared__ __align__(16) float    y_s[STEPS + 1];  // prescaled fcwy*y + fcb
    __shared__ __align__(16) float    XF[128];
    __shared__ __align__(16) float    XG[128];

    const float* Xb = X + (size_t)blockIdx.x * (128 * 128);

    if (tid < 288)   ((uint32_t*)st2)[tid] = 0u;
    if (tid < 128)   c32[0][tid] = 0.f;
    if (tid < STEPS) y_s[tid] = fcW[128] * yh[(size_t)blockIdx.x * STEPS + tid] + fcb[0];
    if (tid < 128)   w2m[tid >> 5][tid & 31] = -2.f * W2[tid];

    const int jA = tid >> 2;   // 0..127
    const int qA = tid & 3;    // 4 threads per j

    // ---- XF[t]=X[t]·fcW[0:128], XG[t]=X[t]·Wff[128:256] (ctx eliminated) ----
    {
        float aF = 0.f, aG = 0.f;
        #pragma unroll
        for (int u = 0; u < 8; ++u) {
            f4v xv = *(const f4v*)(Xb + jA * 128 + qA * 32 + 4 * u);
            f4v fv = *(const f4v*)(fcW + qA * 32 + 4 * u);
            f4v gv = *(const f4v*)(Wff + 128 + qA * 32 + 4 * u);
            aF += xv[0]*fv[0] + xv[1]*fv[1] + xv[2]*fv[2] + xv[3]*fv[3];
            aG += xv[0]*gv[0] + xv[1]*gv[1] + xv[2]*gv[2] + xv[3]*gv[3];
        }
        aF += __shfl_xor(aF, 1); aF += __shfl_xor(aF, 2);
        aG += __shfl_xor(aG, 1); aG += __shfl_xor(aG, 2);
        if (qA == 0) { XF[jA] = aF; XG[jA] = aG; }
    }

    // ---- enc_proj one-time fp32 math, fp16-pair store: EPT_pk[j/2][t] ----
    {
        float w1e[32];
        #pragma unroll
        for (int u = 0; u < 8; ++u) {
            f4v w = *(const f4v*)(W1 + jA * 384 + 256 + qA * 32 + 4 * u);
            w1e[4*u] = w[0]; w1e[4*u+1] = w[1]; w1e[4*u+2] = w[2]; w1e[4*u+3] = w[3];
        }
        for (int tile = 0; tile < 16; ++tile) {
            __syncthreads();
            if (tid < 256) {   // stage 8 rows; f4 slot c4 -> (c4&7)*4+(c4>>3) (broadcast reads)
                int row = tid >> 5, c4 = tid & 31;
                int p = (c4 & 7) * 4 + (c4 >> 3);
                *(f4v*)&Xt[row][p * 4] = *(const f4v*)(Xb + (tile * 8 + row) * 128 + c4 * 4);
            }
            __syncthreads();
            #pragma unroll
            for (int tl = 0; tl < 8; ++tl) {
                float acc = 0.f;
                #pragma unroll
                for (int u = 0; u < 8; ++u) {
                    f4v xv = *(const f4v*)&Xt[tl][(u * 4 + qA) * 4];
                    acc += xv[0]*w1e[4*u] + xv[1]*w1e[4*u+1]
                         + xv[2]*w1e[4*u+2] + xv[3]*w1e[4*u+3];
                }
                acc += __shfl_xor(acc, 1);   // full quad reduce (all quad lanes hold acc)
                acc += __shfl_xor(acc, 2);
                float accp = __shfl_xor(acc, 4);          // partner j's value
                if ((tid & 7) == 0)
                    EPT_pk[tid >> 3][tile * 8 + tl] = pkh2(acc, accp);
            }
        }
    }

    // ---- persistent weights (fp16-pair packed) ----
    uint32_t w1pk[32];   // concat(W1h,W1c)[jA], pairs qA*32..+32 (elems qA*64..+64)
    #pragma unroll
    for (int m = 0; m < 16; ++m) {
        f4v a = *(const f4v*)(W1 + jA * 384 + qA * 64 + 4 * m);
        w1pk[2*m]   = pkh2(a[0], a[1]);
        w1pk[2*m+1] = pkh2(a[2], a[3]);
    }
    const int jD = tid >> 2;               // cell
    const int r  = (tid & 3) * 128 + jD;   // gate row (quad lane q = gate q)
    uint32_t whh[64];                      // Whh[r][:] as 64 h2 pairs
    #pragma unroll
    for (int m = 0; m < 32; ++m) {
        f4v w = *(const f4v*)(Whh + (size_t)r * 128 + 4 * m);
        whh[2*m]   = pkh2(w[0], w[1]);
        whh[2*m+1] = pkh2(w[2], w[3]);
    }
    const float wihv = Wih[r];
    const float bgv  = bih[r] + bhh[r];
    const float b1s  = K2E2 * b1[jA];
    float ytg_last = 0.f;
    __syncthreads();

    // ================= scan: 127 steps, 3 barriers each =================
    for (int s = 0; s < STEPS; ++s) {
        const int cur = s & 1;

        // -- A: hc2[j] = K2E2*(concat(h,c)·W1row[j] + b1[j])  (4 thr/j, dot2)
        {
            float a0 = 0.f, a1 = 0.f;
            const uint32_t* sb = &st2[cur][qA * 36];
            #pragma unroll
            for (int u = 0; u < 8; ++u) {
                u4v sv = *(const u4v*)(sb + 4 * u);
                a0 = dot2(sv[0], w1pk[4*u],   a0);
                a1 = dot2(sv[1], w1pk[4*u+1], a1);
                a0 = dot2(sv[2], w1pk[4*u+2], a0);
                a1 = dot2(sv[3], w1pk[4*u+3], a1);
            }
            float acc = a0 + a1;
            acc += __shfl_xor(acc, 1);
            acc += __shfl_xor(acc, 2);
            if (qA == 0) hc2c[jA >> 5][jA & 31] = fmaf(K2E2, acc, b1s);
        }
        __syncthreads();

        // -- B: quad-per-t logits: e[t] = Σ_h -2*w2[h]*rcp(1+exp2(K2E2*ep+hc2))
        {
            const int t = tid >> 2, q = tid & 3;      // 4 lanes/t, 32 h each
            const uint32_t* ec = &EPT_pk[q * 16][t];  // column t, rows q*16..+16 (stride 133)
            float acc = 0.f;
            #pragma unroll
            for (int u = 0; u < 4; ++u) {
                f4v hcv = *(const f4v*)&hc2c[q][8 * u];
                f4v hcw = *(const f4v*)&hc2c[q][8 * u + 4];
                f4v wv  = *(const f4v*)&w2m[q][8 * u];
                f4v wvw = *(const f4v*)&w2m[q][8 * u + 4];
                #pragma unroll
                for (int k = 0; k < 4; ++k) {
                    uint32_t ep = ec[(4 * u + k) * 133];
                    float hl = (k < 2) ? hcv[2*k]   : hcw[2*k-4];
                    float hh = (k < 2) ? hcv[2*k+1] : hcw[2*k-3];
                    float wl = (k < 2) ? wv[2*k]    : wvw[2*k-4];
                    float wh = (k < 2) ? wv[2*k+1]  : wvw[2*k-3];
                    float z0 = exp2_f(fmaf(h2lo(ep), K2E2, hl));
                    float z1 = exp2_f(fmaf(h2hi(ep), K2E2, hh));
                    acc = fmaf(wl, rcp_f(1.f + z0), acc);
                    acc = fmaf(wh, rcp_f(1.f + z1), acc);
                }
            }
            acc += __shfl_xor(acc, 1);
            acc += __shfl_xor(acc, 2);
            if (q == 0) e_s[t] = acc;
        }
        __syncthreads();

        // -- S: per-wave redundant softmax, NO max pass (|e|<=2*sum|w2|~10, fp32-safe)
        float ytc;
        {
            float v0 = e_s[lane], v1 = e_s[lane + 64];
            float p0 = exp2_f(K2E * v0), p1 = exp2_f(K2E * v1);
            float sp = p0 + p1;
            float sf = p0 * XF[lane] + p1 * XF[lane + 64];
            float sg = p0 * XG[lane] + p1 * XG[lane + 64];
            #pragma unroll
            for (int d = 1; d < 64; d <<= 1) {
                sp += __shfl_xor(sp, d);
                sf += __shfl_xor(sf, d);
                sg += __shfl_xor(sg, d);
            }
            float inv = rcp_f(sp);
            ytc      = sf * inv;
            ytg_last = sg * inv;
        }

        // -- D: gate row dot via dot2; LSTM update fused via quad shuffles
        {
            float yt = ytc + y_s[s];
            float d0 = 0.f, d1 = 0.f, d2 = 0.f, d3 = fmaf(wihv, yt, bgv);
            const uint32_t* hb = &st2[cur][0];
            #pragma unroll
            for (int m = 0; m < 8; ++m) {          // h pairs 0..31 (chunk 0)
                u4v sv = *(const u4v*)(hb + 4 * m);
                d0 = dot2(sv[0], whh[4*m],   d0);
                d1 = dot2(sv[1], whh[4*m+1], d1);
                d2 = dot2(sv[2], whh[4*m+2], d2);
                d3 = dot2(sv[3], whh[4*m+3], d3);
            }
            #pragma unroll
            for (int m = 0; m < 8; ++m) {          // h pairs 32..63 (chunk 1, slot +36)
                u4v sv = *(const u4v*)(hb + 36 + 4 * m);
                d0 = dot2(sv[0], whh[32 + 4*m],   d0);
                d1 = dot2(sv[1], whh[32 + 4*m+1], d1);
                d2 = dot2(sv[2], whh[32 + 4*m+2], d2);
                d3 = dot2(sv[3], whh[32 + 4*m+3], d3);
            }
            float g  = (d0 + d1) + (d2 + d3);
            float gb = __shfl_xor(g, 1);   // at quad lane 0: g=i, gb=f, gc=g, gd=o
            float gc = __shfl_xor(g, 2);
            float gd = __shfl_xor(gb, 2);
            if ((tid & 3) == 0) {
                float co = c32[cur][jD];
                float cn = sig_f(gb) * co + sig_f(g) * tanh_f(gc);
                float hn = sig_f(gd) * tanh_f(cn);
                c32[cur ^ 1][jD] = cn;
                h32[jD] = hn;
                float hp = __shfl_xor(hn, 4);      // partner cell
                float cp = __shfl_xor(cn, 4);
                if ((tid & 7) == 0) {
                    int m0 = tid >> 3;             // pair index 0..63
                    int sl = m0 + 4 * (m0 >> 5);   // chunk-padded slot
                    st2[cur ^ 1][sl]      = pkh2(hn, hp);
                    st2[cur ^ 1][72 + sl] = pkh2(cn, cp);
                }
            }
        }
        __syncthreads();
    }

    // ---- out[b] = h·Wff[0:128] + β_last·XG + bff ----
    if (tid < 64) {
        float v = h32[lane] * Wff[lane] + h32[lane + 64] * Wff[lane + 64];
        #pragma unroll
        for (int d = 1; d < 64; d <<= 1) v += __shfl_xor(v, d);
        if (lane == 0) out[blockIdx.x] = v + ytg_last + bff[0];
    }
}

extern "C" void kernel_launch(void* const* d_in, const int* in_sizes, int n_in,
                              void* d_out, int out_size, void* d_ws, size_t ws_size,
                              hipStream_t stream) {
    dec_kernel<<<Bsz, NTH, 0, stream>>>(
        (const float*)d_in[0],  (const float*)d_in[1],  (const float*)d_in[2],
        (const float*)d_in[3],  (const float*)d_in[4],  (const float*)d_in[5],
        (const float*)d_in[6],  (const float*)d_in[7],  (const float*)d_in[8],
        (const float*)d_in[9],  (const float*)d_in[10], (const float*)d_in[11],
        (const float*)d_in[12], (const float*)d_in[13], (float*)d_out);
}

// Round 9
// 5189.874 us; speedup vs baseline: 5.8598x; 1.1614x over previous
//
#include <hip/hip_runtime.h>
#include <stdint.h>

#define Bsz   4096
#define STEPS 127
#define NTH   512

typedef float    f4v __attribute__((ext_vector_type(4)));
typedef uint32_t u4v __attribute__((ext_vector_type(4)));
typedef _Float16 h2v __attribute__((ext_vector_type(2)));
typedef __fp16   g2v __attribute__((ext_vector_type(2)));

#define K2E  1.4426950408889634f
#define K2E2 2.8853900817779268f

__device__ __forceinline__ float rcp_f(float x) { return __builtin_amdgcn_rcpf(x); }
__device__ __forceinline__ float exp2_f(float x) {
#if __has_builtin(__builtin_amdgcn_exp2f)
    return __builtin_amdgcn_exp2f(x);
#else
    return exp2f(x);
#endif
}
__device__ __forceinline__ float sig_f(float x)  { return rcp_f(1.f + exp2_f(-K2E * x)); }
__device__ __forceinline__ float tanh_f(float x) { return 1.f - 2.f * rcp_f(1.f + exp2_f(K2E2 * x)); }
__device__ __forceinline__ uint32_t pkh2(float a, float b) {
    union { uint32_t u; g2v h; } v;
    v.h = __builtin_amdgcn_cvt_pkrtz(a, b);
    return v.u;
}
__device__ __forceinline__ float h2lo(uint32_t p) {
    union { uint32_t u; h2v h; } v; v.u = p; return (float)v.h[0];
}
__device__ __forceinline__ float h2hi(uint32_t p) {
    union { uint32_t u; h2v h; } v; v.u = p; return (float)v.h[1];
}
__device__ __forceinline__ float dot2(uint32_t a, uint32_t b, float c) {
    union { uint32_t u; h2v h; } x, y;
    x.u = a; y.u = b;
#if __has_builtin(__builtin_amdgcn_fdot2)
    return __builtin_amdgcn_fdot2(x.h, y.h, c, false);
#else
    return c + (float)x.h[0] * (float)y.h[0] + (float)x.h[1] * (float)y.h[1];
#endif
}

// ---- DPP cross-lane (VALU pipe — replaces ds_swizzle/bpermute shuffles) ----
template<int CTRL, int RM, int BM>
__device__ __forceinline__ float dpp_add(float v) {
    union { float f; int i; } s, t;
    s.f = v;
    t.i = __builtin_amdgcn_update_dpp(0, s.i, CTRL, RM, BM, true);
    return v + t.f;
}
template<int CTRL>
__device__ __forceinline__ float dpp_mov(float v) {
    union { float f; int i; } s, t;
    s.f = v;
    t.i = __builtin_amdgcn_mov_dpp(s.i, CTRL, 0xf, 0xf, true);
    return t.f;
}
__device__ __forceinline__ float rd63(float v) {
    union { float f; int i; } s; s.f = v;
    union { int i; float f; } r; r.i = __builtin_amdgcn_readlane(s.i, 63);
    return r.f;
}
// quad sum: all 4 lanes end with the quad total (exact xor butterfly)
__device__ __forceinline__ float qsum(float v) {
    v = dpp_add<0xB1, 0xf, 0xf>(v);   // quad_perm [1,0,3,2] = xor1
    v = dpp_add<0x4E, 0xf, 0xf>(v);   // quad_perm [2,3,0,1] = xor2
    return v;
}
// 64-lane sum -> scalar broadcast (canonical gfx9 DPP reduce, lane63 total)
__device__ __forceinline__ float wsum(float v) {
    v = dpp_add<0x111, 0xf, 0xf>(v);  // row_shr:1
    v = dpp_add<0x112, 0xf, 0xf>(v);  // row_shr:2
    v = dpp_add<0x114, 0xf, 0xe>(v);  // row_shr:4
    v = dpp_add<0x118, 0xf, 0xc>(v);  // row_shr:8
    v = dpp_add<0x142, 0xa, 0xf>(v);  // row_bcast:15 (rows 1,3)
    v = dpp_add<0x143, 0xc, 0xf>(v);  // row_bcast:31 (rows 2,3)
    return rd63(v);
}

// 512 thr, 1 WG/CU (empirical CP behavior). launch_bounds(512,1): VGPR cap 256,
// zero spill risk; occupancy unchanged (8 waves/CU is the observed ceiling).
__global__ __launch_bounds__(NTH, 1)
void dec_kernel(const float* __restrict__ X,    // (B,128,128)
                const float* __restrict__ yh,   // (B,127,1)
                const float* __restrict__ W1,   // (128,384)
                const float* __restrict__ b1,   // (128)
                const float* __restrict__ W2,   // (1,128)
                const float* __restrict__ b2u,  // (1) softmax-invariant
                const float* __restrict__ Wih,  // (512,1)
                const float* __restrict__ Whh,  // (512,128)
                const float* __restrict__ bih,  // (512)
                const float* __restrict__ bhh,  // (512)
                const float* __restrict__ fcW,  // (1,129)
                const float* __restrict__ fcb,  // (1)
                const float* __restrict__ Wff,  // (1,256)
                const float* __restrict__ bff,  // (1)
                float* __restrict__ out)        // (B,1)
{
    const int tid  = threadIdx.x;
    const int lane = tid & 63;

    __shared__ __align__(16) uint32_t EPT_pk[128 * 68];  // enc_proj fp16 pairs, t-major [t][jp], row 68
    __shared__ __align__(16) float    Xt[8][132];        // setup staging
    __shared__ __align__(16) uint32_t st2[2][144];       // half2 pairs of concat(h,c), [4 chunks][36]
    __shared__ __align__(16) float    c32[2][128];       // c carry, fp32
    __shared__ __align__(16) float    h32[128];          // h fp32 (final readout)
    __shared__ __align__(16) float    e_s[128];          // logits
    __shared__ __align__(16) float    hc2c[4][36];       // K2E2*(hc+b1), chunk-padded
    __shared__ __align__(16) float    w2m[4][36];        // -2*w2, chunk-padded
    __shared__ __align__(16) float    y_s[STEPS + 1];    // prescaled fcwy*y + fcb
    __shared__ __align__(16) float    XF[128];
    __shared__ __align__(16) float    XG[128];

    const float* Xb = X + (size_t)blockIdx.x * (128 * 128);

    if (tid < 288)   ((uint32_t*)st2)[tid] = 0u;
    if (tid < 128)   c32[0][tid] = 0.f;
    if (tid < STEPS) y_s[tid] = fcW[128] * yh[(size_t)blockIdx.x * STEPS + tid] + fcb[0];
    if (tid < 128)   w2m[tid >> 5][tid & 31] = -2.f * W2[tid];

    const int jA = tid >> 2;   // 0..127
    const int qA = tid & 3;    // 4 threads per j

    // ---- XF[t]=X[t]·fcW[0:128], XG[t]=X[t]·Wff[128:256] (ctx eliminated) ----
    {
        float aF = 0.f, aG = 0.f;
        #pragma unroll
        for (int u = 0; u < 8; ++u) {
            f4v xv = *(const f4v*)(Xb + jA * 128 + qA * 32 + 4 * u);
            f4v fv = *(const f4v*)(fcW + qA * 32 + 4 * u);
            f4v gv = *(const f4v*)(Wff + 128 + qA * 32 + 4 * u);
            aF += xv[0]*fv[0] + xv[1]*fv[1] + xv[2]*fv[2] + xv[3]*fv[3];
            aG += xv[0]*gv[0] + xv[1]*gv[1] + xv[2]*gv[2] + xv[3]*gv[3];
        }
        aF = qsum(aF);
        aG = qsum(aG);
        if (qA == 0) { XF[jA] = aF; XG[jA] = aG; }
    }

    // ---- enc_proj one-time fp32 math, fp16-pair store t-major: EPT_pk[t][jp] ----
    {
        float w1e[32];
        #pragma unroll
        for (int u = 0; u < 8; ++u) {
            f4v w = *(const f4v*)(W1 + jA * 384 + 256 + qA * 32 + 4 * u);
            w1e[4*u] = w[0]; w1e[4*u+1] = w[1]; w1e[4*u+2] = w[2]; w1e[4*u+3] = w[3];
        }
        for (int tile = 0; tile < 16; ++tile) {
            __syncthreads();
            if (tid < 256) {   // stage 8 rows; f4 slot c4 -> (c4&7)*4+(c4>>3) (broadcast reads)
                int row = tid >> 5, c4 = tid & 31;
                int p = (c4 & 7) * 4 + (c4 >> 3);
                *(f4v*)&Xt[row][p * 4] = *(const f4v*)(Xb + (tile * 8 + row) * 128 + c4 * 4);
            }
            __syncthreads();
            #pragma unroll
            for (int tl = 0; tl < 8; ++tl) {
                float acc = 0.f;
                #pragma unroll
                for (int u = 0; u < 8; ++u) {
                    f4v xv = *(const f4v*)&Xt[tl][(u * 4 + qA) * 4];
                    acc += xv[0]*w1e[4*u] + xv[1]*w1e[4*u+1]
                         + xv[2]*w1e[4*u+2] + xv[3]*w1e[4*u+3];
                }
                acc = qsum(acc);
                float accp = __shfl_xor(acc, 4);          // partner j's value (setup-only)
                if ((tid & 7) == 0)
                    EPT_pk[(tile * 8 + tl) * 68 + (tid >> 3)] = pkh2(acc, accp);
            }
        }
    }

    // ---- persistent weights (fp16-pair packed) ----
    uint32_t w1pk[32];   // concat(W1h,W1c)[jA], pairs qA*32..+32 (elems qA*64..+64)
    #pragma unroll
    for (int m = 0; m < 16; ++m) {
        f4v a = *(const f4v*)(W1 + jA * 384 + qA * 64 + 4 * m);
        w1pk[2*m]   = pkh2(a[0], a[1]);
        w1pk[2*m+1] = pkh2(a[2], a[3]);
    }
    const int jD = tid >> 2;               // cell
    const int r  = (tid & 3) * 128 + jD;   // gate row (quad lane q = gate q)
    uint32_t whh[64];                      // Whh[r][:] as 64 h2 pairs
    #pragma unroll
    for (int m = 0; m < 32; ++m) {
        f4v w = *(const f4v*)(Whh + (size_t)r * 128 + 4 * m);
        whh[2*m]   = pkh2(w[0], w[1]);
        whh[2*m+1] = pkh2(w[2], w[3]);
    }
    const float wihv = Wih[r];
    const float bgv  = bih[r] + bhh[r];
    const float b1s  = K2E2 * b1[jA];
    float ytg_last = 0.f;
    __syncthreads();

    // ================= scan: 127 steps, 3 barriers each =================
    for (int s = 0; s < STEPS; ++s) {
        const int cur = s & 1;

        // -- A: hc2[j] = K2E2*(concat(h,c)·W1row[j] + b1[j])  (4 thr/j, dot2, DPP reduce)
        {
            float a0 = 0.f, a1 = 0.f;
            const uint32_t* sb = &st2[cur][qA * 36];
            #pragma unroll
            for (int u = 0; u < 8; ++u) {
                u4v sv = *(const u4v*)(sb + 4 * u);
                a0 = dot2(sv[0], w1pk[4*u],   a0);
                a1 = dot2(sv[1], w1pk[4*u+1], a1);
                a0 = dot2(sv[2], w1pk[4*u+2], a0);
                a1 = dot2(sv[3], w1pk[4*u+3], a1);
            }
            float acc = qsum(a0 + a1);
            if (qA == 0) hc2c[jA >> 5][jA & 31] = fmaf(K2E2, acc, b1s);
        }
        __syncthreads();

        // -- B: e[t] = Σ_h -2*w2[h]*rcp(1+exp2(K2E2*ep+hc2)); EPT row-reads (4×b128)
        {
            const int t = tid >> 2, q = tid & 3;      // 4 lanes/t, 32 h each
            const uint32_t* er = &EPT_pk[t * 68 + q * 16];
            u4v ee0 = *(const u4v*)(er);
            u4v ee1 = *(const u4v*)(er + 4);
            u4v ee2 = *(const u4v*)(er + 8);
            u4v ee3 = *(const u4v*)(er + 12);
            float acc = 0.f;
            #pragma unroll
            for (int u = 0; u < 4; ++u) {
                u4v ev = (u == 0) ? ee0 : (u == 1) ? ee1 : (u == 2) ? ee2 : ee3;
                f4v hcv = *(const f4v*)&hc2c[q][8 * u];
                f4v hcw = *(const f4v*)&hc2c[q][8 * u + 4];
                f4v wv  = *(const f4v*)&w2m[q][8 * u];
                f4v wvw = *(const f4v*)&w2m[q][8 * u + 4];
                #pragma unroll
                for (int m = 0; m < 4; ++m) {         // pair m: h = 8u+2m, 8u+2m+1
                    uint32_t ep = ev[m];
                    float hl = (m < 2) ? hcv[2*m]   : hcw[2*m-4];
                    float hh = (m < 2) ? hcv[2*m+1] : hcw[2*m-3];
                    float wl = (m < 2) ? wv[2*m]    : wvw[2*m-4];
                    float wh = (m < 2) ? wv[2*m+1]  : wvw[2*m-3];
                    float z0 = exp2_f(fmaf(h2lo(ep), K2E2, hl));
                    float z1 = exp2_f(fmaf(h2hi(ep), K2E2, hh));
                    acc = fmaf(wl, rcp_f(1.f + z0), acc);
                    acc = fmaf(wh, rcp_f(1.f + z1), acc);
                }
            }
            acc = qsum(acc);
            if (q == 0) e_s[t] = acc;
        }
        __syncthreads();

        // -- S: softmax via DPP wave-reduce + readlane broadcast (no max pass, no DS)
        float ytc;
        {
            float v0 = e_s[lane], v1 = e_s[lane + 64];
            float p0 = exp2_f(K2E * v0), p1 = exp2_f(K2E * v1);
            float sp = wsum(p0 + p1);
            float sf = wsum(p0 * XF[lane] + p1 * XF[lane + 64]);
            float sg = wsum(p0 * XG[lane] + p1 * XG[lane + 64]);
            float inv = rcp_f(sp);
            ytc      = sf * inv;
            ytg_last = sg * inv;
        }

        // -- D: gate row dot via dot2; gate transpose via DPP quad_perm
        {
            float yt = ytc + y_s[s];
            float d0 = 0.f, d1 = 0.f, d2 = 0.f, d3 = fmaf(wihv, yt, bgv);
            const uint32_t* hb = &st2[cur][0];
            #pragma unroll
            for (int m = 0; m < 8; ++m) {          // h pairs 0..31 (chunk 0)
                u4v sv = *(const u4v*)(hb + 4 * m);
                d0 = dot2(sv[0], whh[4*m],   d0);
                d1 = dot2(sv[1], whh[4*m+1], d1);
                d2 = dot2(sv[2], whh[4*m+2], d2);
                d3 = dot2(sv[3], whh[4*m+3], d3);
            }
            #pragma unroll
            for (int m = 0; m < 8; ++m) {          // h pairs 32..63 (chunk 1, slot +36)
                u4v sv = *(const u4v*)(hb + 36 + 4 * m);
                d0 = dot2(sv[0], whh[32 + 4*m],   d0);
                d1 = dot2(sv[1], whh[32 + 4*m+1], d1);
                d2 = dot2(sv[2], whh[32 + 4*m+2], d2);
                d3 = dot2(sv[3], whh[32 + 4*m+3], d3);
            }
            float g  = (d0 + d1) + (d2 + d3);
            float gb = dpp_mov<0xB1>(g);    // at quad lane 0: g=i, gb=f, gc=g, gd=o
            float gc = dpp_mov<0x4E>(g);
            float gd = dpp_mov<0x4E>(gb);
            if ((tid & 3) == 0) {
                float co = c32[cur][jD];
                float cn = sig_f(gb) * co + sig_f(g) * tanh_f(gc);
                float hn = sig_f(gd) * tanh_f(cn);
                c32[cur ^ 1][jD] = cn;
                h32[jD] = hn;
                float hp = __shfl_xor(hn, 4);      // partner cell (quarter-wave DS, kept)
                float cp = __shfl_xor(cn, 4);
                if ((tid & 7) == 0) {
                    int m0 = tid >> 3;             // pair index 0..63
                    int sl = m0 + 4 * (m0 >> 5);   // chunk-padded slot
                    st2[cur ^ 1][sl]      = pkh2(hn, hp);
                    st2[cur ^ 1][72 + sl] = pkh2(cn, cp);
                }
            }
        }
        __syncthreads();
    }

    // ---- out[b] = h·Wff[0:128] + β_last·XG + bff ----
    if (tid < 64) {
        float v = h32[lane] * Wff[lane] + h32[lane + 64] * Wff[lane + 64];
        v = wsum(v);
        if (lane == 0) out[blockIdx.x] = v + ytg_last + bff[0];
    }
}

extern "C" void kernel_launch(void* const* d_in, const int* in_sizes, int n_in,
                              void* d_out, int out_size, void* d_ws, size_t ws_size,
                              hipStream_t stream) {
    dec_kernel<<<Bsz, NTH, 0, stream>>>(
        (const float*)d_in[0],  (const float*)d_in[1],  (const float*)d_in[2],
        (const float*)d_in[3],  (const float*)d_in[4],  (const float*)d_in[5],
        (const float*)d_in[6],  (const float*)d_in[7],  (const float*)d_in[8],
        (const float*)d_in[9],  (const float*)d_in[10], (const float*)d_in[11],
        (const float*)d_in[12], (const float*)d_in[13], (float*)d_out);
}